// Round 21
// baseline (376.909 us; speedup 1.0000x reference)
//
#include <hip/hip_runtime.h>
#include <cstdint>
#include <cstddef>

constexpr int D_   = 256;
constexpr int NK_  = 18;
constexpr int NQ_  = 100;
constexpr int BS_  = 8;
constexpr int T_   = NQ_ * BS_ * NK_;   // 14400 tokens
constexpr int LIN_ = 13294;
constexpr int LQ_  = NQ_ * NK_;         // 1800

typedef __attribute__((ext_vector_type(8))) short bfv8;
typedef __attribute__((ext_vector_type(4))) float f32x4;

__device__ __forceinline__ ushort f2b(float f) {
  uint32_t u = __builtin_bit_cast(uint32_t, f);
  u += 0x7fffu + ((u >> 16) & 1u);
  return (ushort)(u >> 16);
}
__device__ __forceinline__ float b2f(ushort h) {
  uint32_t u = ((uint32_t)h) << 16;
  return __builtin_bit_cast(float, u);
}
__device__ __forceinline__ uint pk2(float lo, float hi) {
  return (uint)f2b(lo) | ((uint)f2b(hi) << 16);
}
// async global -> LDS, 16B per lane; lds base must be wave-uniform.
__device__ __forceinline__ void gload16(const ushort* g, ushort* l) {
  __builtin_amdgcn_global_load_lds(
      (const __attribute__((address_space(1))) void*)g,
      (__attribute__((address_space(3))) void*)l, 16, 0, 0);
}

// ---------------------------------------------------------------------------
// Weight conversion arena offsets (off_w + aw_w adjacent -> fused N=384).
// ---------------------------------------------------------------------------
constexpr int WOF0  = 0;        // across_in_w 196608
constexpr int WOF1  = 196608;   // within_in_w 196608
constexpr int WOF2  = 393216;   // across_out_w 65536
constexpr int WOF3  = 458752;   // within_out_w 65536
constexpr int WOF4  = 524288;   // off_w 65536
constexpr int WOF5  = 589824;   // aw_w 32768
constexpr int WOF6  = 622592;   // val_w 65536
constexpr int WOF7  = 688128;   // msout_w 65536
constexpr int WOF8  = 753664;   // lin1_w 262144
constexpr int WOF9  = 1015808;  // lin2_w 262144
constexpr int WOF10 = 1277952;  // lin1p_w 262144
constexpr int WOF11 = 1540096;  // lin2p_w 262144
constexpr int WTOT  = 1802240;

// Weights f32->bf16; block 0 additionally packs the fused off/aw bias.
__global__ __launch_bounds__(256) void conv_weights(
    const float* __restrict__ w0, const float* __restrict__ w1,
    const float* __restrict__ w2, const float* __restrict__ w3,
    const float* __restrict__ w4, const float* __restrict__ w5,
    const float* __restrict__ w6, const float* __restrict__ w7,
    const float* __restrict__ w8, const float* __restrict__ w9,
    const float* __restrict__ w10, const float* __restrict__ w11,
    ushort* __restrict__ out,
    const float* __restrict__ off_b, const float* __restrict__ aw_b,
    float* __restrict__ oab) {
  if (blockIdx.x == 0) {
    int t = threadIdx.x;
    oab[t] = (t < 256) ? off_b[t] : aw_b[t - 256];
    oab[t + 128] = (t + 128 < 256) ? off_b[t + 128] : aw_b[t - 128];
  }
  int i8 = (blockIdx.x * 256 + threadIdx.x) * 8;
  if (i8 >= WTOT) return;
  const float* src; int off;
  if      (i8 < WOF1)  { src = w0;  off = WOF0; }
  else if (i8 < WOF2)  { src = w1;  off = WOF1; }
  else if (i8 < WOF3)  { src = w2;  off = WOF2; }
  else if (i8 < WOF4)  { src = w3;  off = WOF3; }
  else if (i8 < WOF5)  { src = w4;  off = WOF4; }
  else if (i8 < WOF6)  { src = w5;  off = WOF5; }
  else if (i8 < WOF7)  { src = w6;  off = WOF6; }
  else if (i8 < WOF8)  { src = w7;  off = WOF7; }
  else if (i8 < WOF9)  { src = w8;  off = WOF8; }
  else if (i8 < WOF10) { src = w9;  off = WOF9; }
  else if (i8 < WOF11) { src = w10; off = WOF10; }
  else                 { src = w11; off = WOF11; }
  const float4 v0 = *(const float4*)(src + (i8 - off));
  const float4 v1 = *(const float4*)(src + (i8 - off) + 4);
  uint4 o;
  o.x = pk2(v0.x, v0.y); o.y = pk2(v0.z, v0.w);
  o.z = pk2(v1.x, v1.y); o.w = pk2(v1.z, v1.w);
  *(uint4*)(out + i8) = o;
}

// ---------------------------------------------------------------------------
// tgt f32 -> bf16 (mem is consumed directly by gemm_vproj).
// ---------------------------------------------------------------------------
__global__ __launch_bounds__(256) void conv_tgt(
    const float* __restrict__ tgt, ushort* __restrict__ tgtb) {
  int idx = blockIdx.x * 256 + threadIdx.x;
  int r = idx >> 5, c = (idx & 31) * 8;
  if (r >= T_) return;
  const float* p = tgt + (size_t)r * 256 + c;
  float4 v0 = *(const float4*)p, v1 = *(const float4*)(p + 4);
  uint4 o;
  o.x = pk2(v0.x, v0.y); o.y = pk2(v0.z, v0.w);
  o.z = pk2(v1.x, v1.y); o.w = pk2(v1.z, v1.w);
  *(uint4*)(tgtb + (size_t)r * 256 + c) = o;
}

// ---------------------------------------------------------------------------
// Value projection reading mem f32 directly; BM=64 (grid 3324 for TLP, the
// r11-proven occupancy fix), A registers single-depth pipelined, B on
// global_load_lds.  2-barrier loop.
// ---------------------------------------------------------------------------
__global__ __launch_bounds__(256) void gemm_vproj(
    const float* __restrict__ Amem, const ushort* __restrict__ W,
    const float* __restrict__ bias, ushort* __restrict__ C, int M) {
  __shared__ ushort As[64 * 32];     // 4 KB
  __shared__ ushort Bs[128 * 32];    // 8 KB
  const int tid = threadIdx.x;
  const int bm = blockIdx.y * 64, bn = blockIdx.x * 128;
  const int wave = tid >> 6, lane = tid & 63;

  // A staging: 64 rows x 4 chunks = 256 units, 1/thread.
  const int srow = wave * 16 + (lane >> 2);
  const int agch = (lane & 3) ^ (srow & 3);
  int gmA = bm + srow; if (gmA >= M) gmA = M - 1;
  const int ab = gmA / LIN_, ai = gmA - ab * LIN_;
  const float* gAf = Amem + ((size_t)ai * BS_ + ab) * 256 + agch * 8;
  ushort* lA = As + wave * 512 + lane * 8;   // per-lane 16B slot

  // B staging: 128 rows, 2 units/thread.
  const ushort* gB[2]; ushort* lB[2];
#pragma unroll
  for (int j = 0; j < 2; ++j) {
    int row = j * 64 + srow;
    int gch = (lane & 3) ^ (row & 3);
    gB[j] = W + (size_t)(bn + row) * 256 + gch * 8;
    lB[j] = Bs + (j * 4 + wave) * 512;
  }

  const int wm = (wave >> 1) * 32, wn = (wave & 1) * 64;
  const int fr = lane & 15, fk = lane >> 4;
  const int sw = (fk ^ (fr & 3)) << 3;

  float4 ra[2];   // pipelined A registers (8 floats)
  ra[0] = *(const float4*)(gAf);
  ra[1] = *(const float4*)(gAf + 4);

  f32x4 acc[2][4] = {};
  for (int k0 = 0; k0 < 256; k0 += 32) {
#pragma unroll
    for (int j = 0; j < 2; ++j) gload16(gB[j] + k0, lB[j]);
    {
      uint4 o;
      o.x = pk2(ra[0].x, ra[0].y); o.y = pk2(ra[0].z, ra[0].w);
      o.z = pk2(ra[1].x, ra[1].y); o.w = pk2(ra[1].z, ra[1].w);
      *(uint4*)lA = o;
    }
    __syncthreads();
    if (k0 + 32 < 256) {
      ra[0] = *(const float4*)(gAf + k0 + 32);
      ra[1] = *(const float4*)(gAf + k0 + 36);
    }
    bfv8 a[2], b[4];
#pragma unroll
    for (int m = 0; m < 2; ++m)
      a[m] = *(const bfv8*)&As[(wm + m * 16 + fr) * 32 + sw];
#pragma unroll
    for (int n = 0; n < 4; ++n)
      b[n] = *(const bfv8*)&Bs[(wn + n * 16 + fr) * 32 + sw];
#pragma unroll
    for (int m = 0; m < 2; ++m)
#pragma unroll
      for (int n = 0; n < 4; ++n)
        acc[m][n] = __builtin_amdgcn_mfma_f32_16x16x32_bf16(a[m], b[n], acc[m][n], 0, 0, 0);
    __syncthreads();
  }

  const int row0 = (lane >> 4) * 4;
  const int col = lane & 15;
#pragma unroll
  for (int m = 0; m < 2; ++m) {
#pragma unroll
    for (int n = 0; n < 4; ++n) {
      int cn = bn + wn + n * 16 + col;
      float bv = bias[cn];
#pragma unroll
      for (int j = 0; j < 4; ++j) {
        int mg = bm + wm + m * 16 + row0 + j;
        if (mg < M)
          C[(size_t)mg * 256 + cn] = f2b(acc[m][n][j] + bv);
      }
    }
  }
}

// ---------------------------------------------------------------------------
// MFMA GEMM, m97-style gload_lds staging, BM templated (128 or 64), BN=128.
// AMODE 0: plain rows. 2: m=b*1800+lq -> token map row.
// OUTMODE: 0 = f32, 1 = bf16, 2 = bf16 + relu.
// ---------------------------------------------------------------------------
template<int AMODE, int OUTMODE, int BM>
__global__ __launch_bounds__(256) void gemm_mfma(
    const ushort* __restrict__ A, const ushort* __restrict__ W,
    const float* __restrict__ bias, void* __restrict__ Cv,
    int M, int N, int K) {
  constexpr int AJ = BM / 64;
  constexpr int MR = BM / 32;
  __shared__ ushort As[BM * 32];
  __shared__ ushort Bs[128 * 32];
  const int tid = threadIdx.x;
  const int bm = blockIdx.y * BM, bn = blockIdx.x * 128;
  const int wave = tid >> 6, lane = tid & 63;

  const int srow = wave * 16 + (lane >> 2);
  const ushort* gA[AJ]; ushort* lA[AJ];
  const ushort* gB[2];  ushort* lB[2];
#pragma unroll
  for (int j = 0; j < AJ; ++j) {
    int row = j * 64 + srow;
    int gch = (lane & 3) ^ (row & 3);
    int gm = bm + row; if (gm >= M) gm = M - 1;
    int asrc;
    if (AMODE == 0) {
      asrc = gm;
    } else {
      int b = gm / LQ_, lq = gm - b * LQ_;
      int qq = lq / NK_, kk = lq - qq * NK_;
      asrc = qq * (BS_ * NK_) + b * NK_ + kk;
    }
    gA[j] = A + (size_t)asrc * K + gch * 8;
    lA[j] = As + (j * 4 + wave) * 512;
  }
#pragma unroll
  for (int j = 0; j < 2; ++j) {
    int row = j * 64 + srow;
    int gch = (lane & 3) ^ (row & 3);
    gB[j] = W + (size_t)(bn + row) * K + gch * 8;
    lB[j] = Bs + (j * 4 + wave) * 512;
  }

  const int wm = (wave >> 1) * (BM / 2), wn = (wave & 1) * 64;
  const int fr = lane & 15, fk = lane >> 4;
  const int sw = (fk ^ (fr & 3)) << 3;

  f32x4 acc[MR][4] = {};
  for (int k0 = 0; k0 < K; k0 += 32) {
#pragma unroll
    for (int j = 0; j < AJ; ++j) gload16(gA[j] + k0, lA[j]);
#pragma unroll
    for (int j = 0; j < 2; ++j) gload16(gB[j] + k0, lB[j]);
    __syncthreads();
    bfv8 a[MR], b[4];
#pragma unroll
    for (int m = 0; m < MR; ++m)
      a[m] = *(const bfv8*)&As[(wm + m * 16 + fr) * 32 + sw];
#pragma unroll
    for (int n = 0; n < 4; ++n)
      b[n] = *(const bfv8*)&Bs[(wn + n * 16 + fr) * 32 + sw];
#pragma unroll
    for (int m = 0; m < MR; ++m)
#pragma unroll
      for (int n = 0; n < 4; ++n)
        acc[m][n] = __builtin_amdgcn_mfma_f32_16x16x32_bf16(a[m], b[n], acc[m][n], 0, 0, 0);
    __syncthreads();
  }

  const int row0 = (lane >> 4) * 4;
  const int col = lane & 15;
#pragma unroll
  for (int m = 0; m < MR; ++m) {
#pragma unroll
    for (int n = 0; n < 4; ++n) {
      int cn = bn + wn + n * 16 + col;
      float bv = bias[cn];
#pragma unroll
      for (int j = 0; j < 4; ++j) {
        int mg = bm + wm + m * 16 + row0 + j;
        if (mg < M) {
          float o = acc[m][n][j] + bv;
          if (OUTMODE == 2) o = fmaxf(o, 0.f);
          if (OUTMODE == 0) ((float*)Cv)[(size_t)mg * N + cn] = o;
          else ((ushort*)Cv)[(size_t)mg * N + cn] = f2b(o);
        }
      }
    }
  }
}

// ---------------------------------------------------------------------------
// Fused GEMM (N=256) + residual + LayerNorm epilogue (BM=32, bf16 residual).
// LNMODE: 0 = bf16 out + POS, 1 = bf16 out, 2 = f32 out.
// ---------------------------------------------------------------------------
template<int LNMODE>
__global__ __launch_bounds__(256) void gemm_ln(
    const ushort* __restrict__ A, const ushort* __restrict__ W,
    const float* __restrict__ bias, const ushort* __restrict__ Xb,
    const float* __restrict__ POS, const float* __restrict__ G,
    const float* __restrict__ Bb, void* __restrict__ Out, int K) {
  __shared__ float Ep[32][264];              // 33.8 KB; staging aliased below
  ushort* As = (ushort*)&Ep[0][0];           // 32x32  = 2 KB
  ushort* Bs = As + 32 * 32;                 // 256x32 = 16 KB

  const int tid = threadIdx.x;
  const int wave = tid >> 6, lane = tid & 63;
  const int bm = blockIdx.x * 32;

  const int arow = wave * 8 + (lane >> 2);
  const int agch = (lane & 3) ^ (arow & 3);
  const ushort* gA = A + (size_t)(bm + arow) * K + agch * 8;
  ushort* lA = As + wave * 256;
  const int srow = wave * 16 + (lane >> 2);
  const ushort* gB[4]; ushort* lB[4];
#pragma unroll
  for (int j = 0; j < 4; ++j) {
    int row = j * 64 + srow;
    int gch = (lane & 3) ^ (row & 3);
    gB[j] = W + (size_t)row * K + gch * 8;
    lB[j] = Bs + (j * 4 + wave) * 512;
  }

  const int wn = wave * 64;
  const int fr = lane & 15, fk = lane >> 4;
  const int sw = (fk ^ (fr & 3)) << 3;

  f32x4 acc[2][4] = {};
  for (int k0 = 0; k0 < K; k0 += 32) {
    if (lane < 32) gload16(gA + k0, lA);
#pragma unroll
    for (int j = 0; j < 4; ++j) gload16(gB[j] + k0, lB[j]);
    __syncthreads();
    bfv8 a[2], b[4];
#pragma unroll
    for (int m = 0; m < 2; ++m)
      a[m] = *(const bfv8*)&As[(m * 16 + fr) * 32 + sw];
#pragma unroll
    for (int n = 0; n < 4; ++n)
      b[n] = *(const bfv8*)&Bs[(wn + n * 16 + fr) * 32 + sw];
#pragma unroll
    for (int m = 0; m < 2; ++m)
#pragma unroll
      for (int n = 0; n < 4; ++n)
        acc[m][n] = __builtin_amdgcn_mfma_f32_16x16x32_bf16(a[m], b[n], acc[m][n], 0, 0, 0);
    __syncthreads();
  }

  const int row0 = (lane >> 4) * 4;
  const int col = lane & 15;
  float bv[4];
#pragma unroll
  for (int n = 0; n < 4; ++n) bv[n] = bias[wn + n * 16 + col];

  const float4 g4 = *(const float4*)(G + lane * 4);
  const float4 bb4 = *(const float4*)(Bb + lane * 4);

#pragma unroll
  for (int m = 0; m < 2; ++m)
#pragma unroll
    for (int n = 0; n < 4; ++n)
#pragma unroll
      for (int j = 0; j < 4; ++j)
        Ep[m * 16 + row0 + j][wn + n * 16 + col] = acc[m][n][j] + bv[n];
  __syncthreads();

  for (int rr = 0; rr < 8; ++rr) {
    int lrow = wave * 8 + rr;
    size_t off = (size_t)(bm + lrow) * 256 + lane * 4;
    float4 ev = *(const float4*)&Ep[lrow][lane * 4];
    ushort4 x4 = *(const ushort4*)(Xb + off);
    float4 v = make_float4(b2f(x4.x) + ev.x, b2f(x4.y) + ev.y,
                           b2f(x4.z) + ev.z, b2f(x4.w) + ev.w);
    float s = v.x + v.y + v.z + v.w;
#pragma unroll
    for (int o = 32; o; o >>= 1) s += __shfl_xor(s, o);
    float mu = s * (1.0f / 256.0f);
    float4 c = make_float4(v.x - mu, v.y - mu, v.z - mu, v.w - mu);
    float q = c.x * c.x + c.y * c.y + c.z * c.z + c.w * c.w;
#pragma unroll
    for (int o = 32; o; o >>= 1) q += __shfl_xor(q, o);
    float rs = rsqrtf(q * (1.0f / 256.0f) + 1e-5f);
    float4 o4;
    o4.x = c.x * rs * g4.x + bb4.x;
    o4.y = c.y * rs * g4.y + bb4.y;
    o4.z = c.z * rs * g4.z + bb4.z;
    o4.w = c.w * rs * g4.w + bb4.w;
    if (LNMODE == 0) {
      float4 pv = *(const float4*)(POS + off);
      o4.x += pv.x; o4.y += pv.y; o4.z += pv.z; o4.w += pv.w;
    }
    if (LNMODE == 2) {
      *(float4*)((float*)Out + off) = o4;
    } else {
      ushort4 ob;
      ob.x = f2b(o4.x); ob.y = f2b(o4.y); ob.z = f2b(o4.z); ob.w = f2b(o4.w);
      *(ushort4*)((ushort*)Out + off) = ob;
    }
  }
}

// ---------------------------------------------------------------------------
// Across-attention via MFMA (unchanged, known-good).
// ---------------------------------------------------------------------------
__global__ __launch_bounds__(256) void attn_across_mfma(
    const ushort* __restrict__ QKV, ushort* __restrict__ O) {
  __shared__ ushort Qs[112][40];
  __shared__ ushort Ks[112][40];
  __shared__ ushort Vt[32][136];
  __shared__ ushort Ps[112][136];
  const int b = blockIdx.x >> 3, h = blockIdx.x & 7;
  const int tid = threadIdx.x;

  for (int idx = tid; idx < 112 * 16; idx += 256) {
    int r = idx >> 4, du = (idx & 15) * 2;
    uint q = 0, k = 0;
    if (r < 100) {
      size_t base = ((size_t)r * 144 + b) * 768 + h * 32 + du;
      q = *(const uint*)(QKV + base);
      k = *(const uint*)(QKV + base + 256);
    }
    *(uint*)&Qs[r][du] = q;
    *(uint*)&Ks[r][du] = k;
  }
  for (int idx = tid; idx < 128 * 32; idx += 256) {
    int s = idx >> 5, d = idx & 31;
    ushort v = 0;
    if (s < 100) v = QKV[((size_t)s * 144 + b) * 768 + 512 + h * 32 + d];
    Vt[d][s] = v;
  }
  for (int idx = tid; idx < 112 * 8; idx += 256) {
    int r = idx >> 3, c = 112 + (idx & 7) * 2;
    *(uint*)&Ps[r][c] = 0;
  }
  __syncthreads();

  const int wave = tid >> 6, lane = tid & 63;
  const int fr = lane & 15, fk = lane >> 4;
  const float scale = 0.17677669529663687f;

#pragma unroll
  for (int mi = 0; mi < 2; ++mi) {
    const int mt = wave + mi * 4;
    if (mt < 7) {
      bfv8 aq = *(const bfv8*)&Qs[mt * 16 + fr][fk * 8];
      f32x4 sacc[7];
#pragma unroll
      for (int nt = 0; nt < 7; ++nt) {
        bfv8 bk = *(const bfv8*)&Ks[nt * 16 + fr][fk * 8];
        f32x4 z = {0.f, 0.f, 0.f, 0.f};
        sacc[nt] = __builtin_amdgcn_mfma_f32_16x16x32_bf16(aq, bk, z, 0, 0, 0);
      }
      const bool maskc = (lane & 15) >= 4;
#pragma unroll
      for (int j = 0; j < 4; ++j) {
        float v[7];
        float mx = -1e30f;
#pragma unroll
        for (int nt = 0; nt < 7; ++nt) {
          float s = sacc[nt][j] * scale;
          if (nt == 6 && maskc) s = -1e30f;
          v[nt] = s;
          mx = fmaxf(mx, s);
        }
        mx = fmaxf(mx, __shfl_xor(mx, 1));
        mx = fmaxf(mx, __shfl_xor(mx, 2));
        mx = fmaxf(mx, __shfl_xor(mx, 4));
        mx = fmaxf(mx, __shfl_xor(mx, 8));
        float sum = 0.f;
#pragma unroll
        for (int nt = 0; nt < 7; ++nt) {
          v[nt] = __expf(v[nt] - mx);
          sum += v[nt];
        }
        sum += __shfl_xor(sum, 1);
        sum += __shfl_xor(sum, 2);
        sum += __shfl_xor(sum, 4);
        sum += __shfl_xor(sum, 8);
        float inv = 1.f / sum;
        int row = mt * 16 + (lane >> 4) * 4 + j;
#pragma unroll
        for (int nt = 0; nt < 7; ++nt)
          Ps[row][nt * 16 + (lane & 15)] = f2b(v[nt] * inv);
      }
    }
  }
  __syncthreads();

  f32x4 oacc[2][2] = {};
#pragma unroll
  for (int mi = 0; mi < 2; ++mi) {
    const int mt = wave + mi * 4;
    if (mt < 7) {
#pragma unroll
      for (int ks = 0; ks < 4; ++ks) {
        bfv8 ap = *(const bfv8*)&Ps[mt * 16 + fr][ks * 32 + fk * 8];
#pragma unroll
        for (int n = 0; n < 2; ++n) {
          bfv8 bv = *(const bfv8*)&Vt[n * 16 + fr][ks * 32 + fk * 8];
          oacc[mi][n] = __builtin_amdgcn_mfma_f32_16x16x32_bf16(ap, bv, oacc[mi][n], 0, 0, 0);
        }
      }
#pragma unroll
      for (int n = 0; n < 2; ++n) {
#pragma unroll
        for (int j = 0; j < 4; ++j) {
          int q = mt * 16 + (lane >> 4) * 4 + j;
          if (q < 100) {
            O[((size_t)q * 144 + b) * 256 + h * 32 + n * 16 + (lane & 15)] =
                f2b(oacc[mi][n][j]);
          }
        }
      }
    }
  }
}

// ---------------------------------------------------------------------------
// Within-attention (unchanged, known-good).
// ---------------------------------------------------------------------------
__global__ __launch_bounds__(256) void attn_within(
    const ushort* __restrict__ QKV, ushort* __restrict__ O) {
  constexpr int ST = 258;
  __shared__ ushort Qs[18 * ST];
  __shared__ ushort Ks[18 * ST];
  __shared__ ushort Vs[18 * ST];
  const int bidx = blockIdx.x;
  const int qq = bidx >> 3, bb = bidx & 7;
  const int tid = threadIdx.x;
  for (int idx = tid; idx < 18 * 128; idx += 256) {
    int r = idx >> 7, j2 = (idx & 127) * 2;
    size_t base = ((size_t)qq * 144 + bb * 18 + r) * 768 + j2;
    *(uint*)&Qs[r * ST + j2] = *(const uint*)(QKV + base);
    *(uint*)&Ks[r * ST + j2] = *(const uint*)(QKV + base + 256);
    *(uint*)&Vs[r * ST + j2] = *(const uint*)(QKV + base + 512);
  }
  __syncthreads();
  const int wave = tid >> 6, lane = tid & 63;
  const int h = wave * 2 + (lane >> 5);
  const int li = lane & 31;
  const int hd = h * 32;
  const float scale = 0.17677669529663687f;
  const bool kv = li < 18;
  for (int s = 0; s < 18; ++s) {
    float sc = 0.f;
    if (kv) {
      const ushort* qrow = &Qs[s * ST + hd];
      const ushort* krow = &Ks[li * ST + hd];
#pragma unroll 8
      for (int d = 0; d < 32; ++d) sc += b2f(qrow[d]) * b2f(krow[d]);
    }
    sc = kv ? sc * scale : -1e30f;
    float mx = sc;
    mx = fmaxf(mx, __shfl_xor(mx, 16));
    mx = fmaxf(mx, __shfl_xor(mx, 8));
    mx = fmaxf(mx, __shfl_xor(mx, 4));
    mx = fmaxf(mx, __shfl_xor(mx, 2));
    mx = fmaxf(mx, __shfl_xor(mx, 1));
    float e = kv ? __expf(sc - mx) : 0.f;
    float sum = e;
    sum += __shfl_xor(sum, 16);
    sum += __shfl_xor(sum, 8);
    sum += __shfl_xor(sum, 4);
    sum += __shfl_xor(sum, 2);
    sum += __shfl_xor(sum, 1);
    float p = e / sum;
    float o = 0.f;
    const int half = lane & 32;
#pragma unroll
    for (int k = 0; k < 18; ++k) {
      float pk = __shfl(p, half + k);
      o += pk * b2f(Vs[k * ST + hd + li]);
    }
    O[((size_t)qq * 144 + bb * 18 + s) * 256 + hd + li] = f2b(o);
  }
}

// ---------------------------------------------------------------------------
// Deformable sampling, two-phase (unchanged, known-good).
// ---------------------------------------------------------------------------
__global__ __launch_bounds__(256) void deform_sample(
    const float* __restrict__ OFFAW, const ushort* __restrict__ V,
    const float* __restrict__ REF, ushort* __restrict__ OUT) {
  __shared__ uint2 sDesc[32 * 65];
  const int tid = threadIdx.x;
  const int m0 = blockIdx.x * 4;

  const int WH[4] = {100, 50, 25, 13};
  const int STl[4] = {0, 10000, 12500, 13125};

#pragma unroll
  for (int dd = 0; dd < 2; ++dd) {
    const int desc = tid + dd * 256;
    const int g = desc >> 7, rem = desc & 127;
    const int h = rem >> 4, lp = rem & 15, li = lp >> 2, p = lp & 3;
    const int m = m0 + g;
    const int b = m / LQ_, lq = m - b * LQ_;

    float awv = OFFAW[(size_t)m * 384 + 256 + h * 16 + lp];
    float mx = awv;
    mx = fmaxf(mx, __shfl_xor(mx, 8, 16));
    mx = fmaxf(mx, __shfl_xor(mx, 4, 16));
    mx = fmaxf(mx, __shfl_xor(mx, 2, 16));
    mx = fmaxf(mx, __shfl_xor(mx, 1, 16));
    float e = __expf(awv - mx);
    float sm = e;
    sm += __shfl_xor(sm, 8, 16);
    sm += __shfl_xor(sm, 4, 16);
    sm += __shfl_xor(sm, 2, 16);
    sm += __shfl_xor(sm, 1, 16);
    const float aw = e / sm;

    const float* offp = OFFAW + (size_t)m * 384 + h * 32 + li * 8 + p * 2;
    const float ox = offp[0], oy = offp[1];
    const float rx = REF[(((size_t)lq * 8 + b) * 4 + li) * 2 + 0];
    const float ry = REF[(((size_t)lq * 8 + b) * 4 + li) * 2 + 1];
    const int Wl = WH[li], st = STl[li];
    const float fW = (float)Wl;
    const float x = fmaf(rx, fW, ox) - 0.5f;
    const float y = fmaf(ry, fW, oy) - 0.5f;
    const float x0f = floorf(x), y0f = floorf(y);
    const float lx = x - x0f, ly = y - y0f;
    const int x0 = (int)x0f, y0 = (int)y0f;
    const int base = (g * 8 + h) * 65 + lp * 4;
#pragma unroll
    for (int c = 0; c < 4; ++c) {
      const int cx = c & 1, cy = c >> 1;
      const int xi = x0 + cx, yi = y0 + cy;
      const bool va = (xi >= 0) && (xi < Wl) && (yi >= 0) && (yi < Wl);
      const int xc = min(max(xi, 0), Wl - 1);
      const int yc = min(max(yi, 0), Wl - 1);
      const float wx = cx ? lx : (1.f - lx);
      const float wy = cy ? ly : (1.f - ly);
      const float wgt = va ? aw * wx * wy : 0.f;
      uint2 dv;
      dv.x = (uint)(st + yc * Wl + xc);
      dv.y = __builtin_bit_cast(uint, wgt);
      sDesc[base + c] = dv;
    }
  }
  __syncthreads();

  const int g = tid >> 6;
  const int h = (tid >> 3) & 7;
  const int d4 = (tid & 7) * 4;
  const int m = m0 + g;
  const int b = m / LQ_, lq = m - b * LQ_;
  const int qq = lq / NK_, kk = lq - qq * NK_;
  const ushort* Vg = V + ((size_t)b * LIN_) * 256 + h * 32 + d4;
  const int dbase = (g * 8 + h) * 65;
  float a0 = 0.f, a1 = 0.f, a2 = 0.f, a3 = 0.f;
#pragma unroll
  for (int lp = 0; lp < 16; ++lp) {
#pragma unroll
    for (int c = 0; c < 4; ++c) {
      const uint2 dv = sDesc[dbase + lp * 4 + c];
      const float w = __builtin_bit_cast(float, dv.y);
      const ushort4 v = *(const ushort4*)(Vg + (size_t)dv.x * 256);
      a0 = fmaf(w, b2f(v.x), a0);
      a1 = fmaf(w, b2f(v.y), a1);
      a2 = fmaf(w, b2f(v.z), a2);
      a3 = fmaf(w, b2f(v.w), a3);
    }
  }
  const size_t tok = (size_t)qq * 144 + b * 18 + kk;
  ushort4 o;
  o.x = f2b(a0); o.y = f2b(a1); o.z = f2b(a2); o.w = f2b(a3);
  *(ushort4*)(OUT + tok * 256 + h * 32 + d4) = o;
}

// ---------------------------------------------------------------------------
extern "C" void kernel_launch(void* const* d_in, const int* in_sizes, int n_in,
                              void* d_out, int out_size, void* d_ws, size_t ws_size,
                              hipStream_t stream) {
  const float* tgt  = (const float*)d_in[0];
  const float* pos  = (const float*)d_in[1];
  const float* ref  = (const float*)d_in[2];
  const float* mem  = (const float*)d_in[3];
  const float* across_in_w  = (const float*)d_in[4];
  const float* across_in_b  = (const float*)d_in[5];
  const float* across_out_w = (const float*)d_in[6];
  const float* across_out_b = (const float*)d_in[7];
  const float* within_in_w  = (const float*)d_in[8];
  const float* within_in_b  = (const float*)d_in[9];
  const float* within_out_w = (const float*)d_in[10];
  const float* within_out_b = (const float*)d_in[11];
  const float* off_w  = (const float*)d_in[12];
  const float* off_b  = (const float*)d_in[13];
  const float* aw_w   = (const float*)d_in[14];
  const float* aw_b   = (const float*)d_in[15];
  const float* val_w  = (const float*)d_in[16];
  const float* val_b  = (const float*)d_in[17];
  const float* msout_w = (const float*)d_in[18];
  const float* msout_b = (const float*)d_in[19];
  const float* lin1_w  = (const float*)d_in[20];
  const float* lin1_b  = (const float*)d_in[21];
  const float* lin2_w  = (const float*)d_in[22];
  const float* lin2_b  = (const float*)d_in[23];
  const float* lin1p_w = (const float*)d_in[24];
  const float* lin1p_b = (const float*)d_in[25];
  const float* lin2p_w = (const float*)d_in[26];
  const float* lin2p_b = (const float*)d_in[27];
  const float* across_norm_g = (const float*)d_in[28];
  const float* across_norm_b = (const float*)d_in[29];
  const float* within_norm_g = (const float*)d_in[30];
  const float* within_norm_b = (const float*)d_in[31];
  const float* norm1_g = (const float*)d_in[32];
  const float* norm1_b = (const float*)d_in[33];
  const float* norm2_g = (const float*)d_in[34];
  const float* norm2_b = (const float*)d_in[35];
  const float* norm2p_g = (const float*)d_in[36];
  const float* norm2p_b = (const float*)d_in[37];

  // ---- workspace layout (QKVb/R1 and tgtb/OFFAW share) ----
  char* w = (char*)d_ws;
  ushort* Wb    = (ushort*)w;  w += 3604480;                         // weights bf16
  ushort* QKVb  = (ushort*)w;  w += (size_t)(BS_ * LIN_) * 256 * 2;  // 54.5MB region (QKV uses 22.1MB)
  ushort* AOb   = (ushort*)w;  w += (size_t)T_ * 256 * 2;            // 7.37MB (also SMPb)
  ushort* CTb   = (ushort*)w;  w += (size_t)T_ * 256 * 2;            // 7.37MB (bf16 residual stream)
  ushort* Vb    = (ushort*)w;  w += (size_t)(BS_ * LIN_) * 256 * 2;  // 54.5MB (also Uff)
  float*  R2    = (float*)w;   w += (size_t)T_ * 384 * 4;            // 22.1MB: tgtb then OFFAW
  float*  OAB   = (float*)w;   w += 384 * 4;
  ushort* tgtb  = (ushort*)R2;
  float*  OFFAW = R2;       // written after tgtb's last use (step 5; tgtb last read in step 4)
  ushort* Uff   = Vb;
  ushort* SMPb  = AOb;

  ushort* W_across_in  = Wb + WOF0;
  ushort* W_within_in  = Wb + WOF1;
  ushort* W_across_out = Wb + WOF2;
  ushort* W_within_out = Wb + WOF3;
  ushort* W_offaw      = Wb + WOF4;   // off rows 0..255, aw rows 256..383
  ushort* W_val        = Wb + WOF6;
  ushort* W_msout      = Wb + WOF7;
  ushort* W_lin1       = Wb + WOF8;
  ushort* W_lin2       = Wb + WOF9;
  ushort* W_lin1p      = Wb + WOF10;
  ushort* W_lin2p      = Wb + WOF11;

  dim3 blk(256);
  const int MT = T_;                 // 14400
  const int MV = BS_ * LIN_;         // 106352
  const int MV64 = (MV + 63) / 64;   // 1662 (BM=64 vproj grid)
  const int MT64 = MT / 64;          // 225 (BM=64 GEMM grid)
  const int MT32 = MT / 32;          // 450 (gemm_ln grid)

  // 0. conversions (weights+bias fused; tgt only — mem is read directly)
  conv_weights<<<dim3((WTOT / 8 + 255) / 256), blk, 0, stream>>>(
      across_in_w, within_in_w, across_out_w, within_out_w, off_w, aw_w,
      val_w, msout_w, lin1_w, lin2_w, lin1p_w, lin2p_w, Wb, off_b, aw_b, OAB);
  conv_tgt<<<dim3(MT * 32 / 256), blk, 0, stream>>>(tgt, tgtb);
  // 1. value projection (mem f32 direct, BM=64 for TLP, A-pipelined) -> Vb
  gemm_vproj<<<dim3(2, MV64), blk, 0, stream>>>(
      mem, W_val, val_b, Vb, MV);
  // 2. across in-proj -> QKVb
  gemm_mfma<0, 1, 64><<<dim3(6, MT64), blk, 0, stream>>>(
      tgtb, W_across_in, across_in_b, QKVb, MT, 768, 256);
  // 3. across attention -> AOb
  attn_across_mfma<<<dim3(144 * 8), blk, 0, stream>>>(QKVb, AOb);
  // 4. across out-proj + LN(tgtb + .) + pos -> CTb (bf16)
  gemm_ln<0><<<dim3(MT32), blk, 0, stream>>>(
      AOb, W_across_out, across_out_b, tgtb, pos,
      across_norm_g, across_norm_b, CTb, 256);
  // 5. fused off+aw (token map) -> OFFAW (overwrites tgtb; tgtb dead)
  gemm_mfma<2, 0, 64><<<dim3(3, MT64), blk, 0, stream>>>(
      CTb, W_offaw, OAB, OFFAW, MT, 384, 256);
  // 6. bilinear sampling -> SMPb
  deform_sample<<<dim3(T_ / 4), blk, 0, stream>>>(OFFAW, Vb, ref, SMPb);
  // 7. msout + norm1(CTb + .) -> CTb (in-place, block-local safe)
  gemm_ln<1><<<dim3(MT32), blk, 0, stream>>>(
      SMPb, W_msout, msout_b, CTb, nullptr,
      norm1_g, norm1_b, CTb, 256);
  // 8. lin1 (+relu) -> Uff
  gemm_mfma<0, 2, 64><<<dim3(8, MT64), blk, 0, stream>>>(
      CTb, W_lin1, lin1_b, Uff, MT, 1024, 256);
  // 9. lin2 + norm2(CTb + .) + pos -> CTb
  gemm_ln<0><<<dim3(MT32), blk, 0, stream>>>(
      Uff, W_lin2, lin2_b, CTb, pos,
      norm2_g, norm2_b, CTb, 1024);
  // 10. within in-proj -> QKVb
  gemm_mfma<0, 1, 64><<<dim3(6, MT64), blk, 0, stream>>>(
      CTb, W_within_in, within_in_b, QKVb, MT, 768, 256);
  // 11. within attention -> AOb
  attn_within<<<dim3(NQ_ * BS_), blk, 0, stream>>>(QKVb, AOb);
  // 12. within out-proj + within_norm(CTb + .) -> CTb
  gemm_ln<1><<<dim3(MT32), blk, 0, stream>>>(
      AOb, W_within_out, within_out_b, CTb, nullptr,
      within_norm_g, within_norm_b, CTb, 256);
  // 13. lin1p (+relu) -> Uff
  gemm_mfma<0, 2, 64><<<dim3(8, MT64), blk, 0, stream>>>(
      CTb, W_lin1p, lin1p_b, Uff, MT, 1024, 256);
  // 14. lin2p + norm2p(CTb + .) -> d_out (f32)
  gemm_ln<2><<<dim3(MT32), blk, 0, stream>>>(
      Uff, W_lin2p, lin2p_b, CTb, nullptr,
      norm2p_g, norm2p_b, (float*)d_out, 1024);
}

// Round 22
// 376.226 us; speedup vs baseline: 1.0018x; 1.0018x over previous
//
#include <hip/hip_runtime.h>
#include <cstdint>
#include <cstddef>

constexpr int D_   = 256;
constexpr int NK_  = 18;
constexpr int NQ_  = 100;
constexpr int BS_  = 8;
constexpr int T_   = NQ_ * BS_ * NK_;   // 14400 tokens
constexpr int LIN_ = 13294;
constexpr int LQ_  = NQ_ * NK_;         // 1800

typedef __attribute__((ext_vector_type(8))) short bfv8;
typedef __attribute__((ext_vector_type(4))) float f32x4;

__device__ __forceinline__ ushort f2b(float f) {
  uint32_t u = __builtin_bit_cast(uint32_t, f);
  u += 0x7fffu + ((u >> 16) & 1u);
  return (ushort)(u >> 16);
}
__device__ __forceinline__ float b2f(ushort h) {
  uint32_t u = ((uint32_t)h) << 16;
  return __builtin_bit_cast(float, u);
}
__device__ __forceinline__ uint pk2(float lo, float hi) {
  return (uint)f2b(lo) | ((uint)f2b(hi) << 16);
}
// async global -> LDS, 16B per lane; lds base must be wave-uniform.
__device__ __forceinline__ void gload16(const ushort* g, ushort* l) {
  __builtin_amdgcn_global_load_lds(
      (const __attribute__((address_space(1))) void*)g,
      (__attribute__((address_space(3))) void*)l, 16, 0, 0);
}

// ---------------------------------------------------------------------------
// Weight conversion arena offsets (off_w + aw_w adjacent -> fused N=384).
// ---------------------------------------------------------------------------
constexpr int WOF0  = 0;        // across_in_w 196608
constexpr int WOF1  = 196608;   // within_in_w 196608
constexpr int WOF2  = 393216;   // across_out_w 65536
constexpr int WOF3  = 458752;   // within_out_w 65536
constexpr int WOF4  = 524288;   // off_w 65536
constexpr int WOF5  = 589824;   // aw_w 32768
constexpr int WOF6  = 622592;   // val_w 65536
constexpr int WOF7  = 688128;   // msout_w 65536
constexpr int WOF8  = 753664;   // lin1_w 262144
constexpr int WOF9  = 1015808;  // lin2_w 262144
constexpr int WOF10 = 1277952;  // lin1p_w 262144
constexpr int WOF11 = 1540096;  // lin2p_w 262144
constexpr int WTOT  = 1802240;

// Weights f32->bf16; block 0 additionally packs the fused off/aw bias.
__global__ __launch_bounds__(256) void conv_weights(
    const float* __restrict__ w0, const float* __restrict__ w1,
    const float* __restrict__ w2, const float* __restrict__ w3,
    const float* __restrict__ w4, const float* __restrict__ w5,
    const float* __restrict__ w6, const float* __restrict__ w7,
    const float* __restrict__ w8, const float* __restrict__ w9,
    const float* __restrict__ w10, const float* __restrict__ w11,
    ushort* __restrict__ out,
    const float* __restrict__ off_b, const float* __restrict__ aw_b,
    float* __restrict__ oab) {
  if (blockIdx.x == 0) {
    int t = threadIdx.x;
    oab[t] = (t < 256) ? off_b[t] : aw_b[t - 256];
    oab[t + 128] = (t + 128 < 256) ? off_b[t + 128] : aw_b[t - 128];
  }
  int i8 = (blockIdx.x * 256 + threadIdx.x) * 8;
  if (i8 >= WTOT) return;
  const float* src; int off;
  if      (i8 < WOF1)  { src = w0;  off = WOF0; }
  else if (i8 < WOF2)  { src = w1;  off = WOF1; }
  else if (i8 < WOF3)  { src = w2;  off = WOF2; }
  else if (i8 < WOF4)  { src = w3;  off = WOF3; }
  else if (i8 < WOF5)  { src = w4;  off = WOF4; }
  else if (i8 < WOF6)  { src = w5;  off = WOF5; }
  else if (i8 < WOF7)  { src = w6;  off = WOF6; }
  else if (i8 < WOF8)  { src = w7;  off = WOF7; }
  else if (i8 < WOF9)  { src = w8;  off = WOF8; }
  else if (i8 < WOF10) { src = w9;  off = WOF9; }
  else if (i8 < WOF11) { src = w10; off = WOF10; }
  else                 { src = w11; off = WOF11; }
  const float4 v0 = *(const float4*)(src + (i8 - off));
  const float4 v1 = *(const float4*)(src + (i8 - off) + 4);
  uint4 o;
  o.x = pk2(v0.x, v0.y); o.y = pk2(v0.z, v0.w);
  o.z = pk2(v1.x, v1.y); o.w = pk2(v1.z, v1.w);
  *(uint4*)(out + i8) = o;
}

// ---------------------------------------------------------------------------
// tgt f32 -> bf16 (mem is consumed directly by gemm_vproj).
// ---------------------------------------------------------------------------
__global__ __launch_bounds__(256) void conv_tgt(
    const float* __restrict__ tgt, ushort* __restrict__ tgtb) {
  int idx = blockIdx.x * 256 + threadIdx.x;
  int r = idx >> 5, c = (idx & 31) * 8;
  if (r >= T_) return;
  const float* p = tgt + (size_t)r * 256 + c;
  float4 v0 = *(const float4*)p, v1 = *(const float4*)(p + 4);
  uint4 o;
  o.x = pk2(v0.x, v0.y); o.y = pk2(v0.z, v0.w);
  o.z = pk2(v1.x, v1.y); o.w = pk2(v1.z, v1.w);
  *(uint4*)(tgtb + (size_t)r * 256 + c) = o;
}

// ---------------------------------------------------------------------------
// Value projection reading mem f32 directly (reorder folded into A-row map;
// f32->bf16 in A staging).  A registers single-depth pipelined: A(k+1)
// loaded right after the first barrier so its HBM latency hides under the
// MFMA phase.  B stays on global_load_lds.  2-barrier BM=128/BN=128 loop.
// Best-measured config (r18: 373.5 us total, vproj ~78 us).
// ---------------------------------------------------------------------------
__global__ __launch_bounds__(256) void gemm_vproj(
    const float* __restrict__ Amem, const ushort* __restrict__ W,
    const float* __restrict__ bias, ushort* __restrict__ C, int M) {
  __shared__ ushort As[128 * 32];
  __shared__ ushort Bs[128 * 32];
  const int tid = threadIdx.x;
  const int bm = blockIdx.y * 128, bn = blockIdx.x * 128;
  const int wave = tid >> 6, lane = tid & 63;

  const int srow = wave * 16 + (lane >> 2);
  const float* gAf[2]; ushort* lA[2];
  const ushort* gB[2]; ushort* lB[2];
#pragma unroll
  for (int j = 0; j < 2; ++j) {
    int row = j * 64 + srow;
    int gch = (lane & 3) ^ (row & 3);
    int gm = bm + row; if (gm >= M) gm = M - 1;
    int b = gm / LIN_, i = gm - b * LIN_;       // output row b*LIN+i
    gAf[j] = Amem + ((size_t)i * BS_ + b) * 256 + gch * 8;  // mem row i*8+b
    lA[j] = As + (j * 4 + wave) * 512 + lane * 8;           // per-lane 16B slot
    gB[j] = W + (size_t)(bn + row) * 256 + gch * 8;
    lB[j] = Bs + (j * 4 + wave) * 512;
  }

  const int wm = (wave >> 1) * 64, wn = (wave & 1) * 64;
  const int fr = lane & 15, fk = lane >> 4;
  const int sw = (fk ^ (fr & 3)) << 3;

  float4 ra[2][2];   // pipelined A registers (2 rows x 8 floats)
#pragma unroll
  for (int j = 0; j < 2; ++j) {
    ra[j][0] = *(const float4*)(gAf[j]);
    ra[j][1] = *(const float4*)(gAf[j] + 4);
  }

  f32x4 acc[4][4] = {};
  for (int k0 = 0; k0 < 256; k0 += 32) {
#pragma unroll
    for (int j = 0; j < 2; ++j) gload16(gB[j] + k0, lB[j]);
#pragma unroll
    for (int j = 0; j < 2; ++j) {
      uint4 o;
      o.x = pk2(ra[j][0].x, ra[j][0].y); o.y = pk2(ra[j][0].z, ra[j][0].w);
      o.z = pk2(ra[j][1].x, ra[j][1].y); o.w = pk2(ra[j][1].z, ra[j][1].w);
      *(uint4*)lA[j] = o;
    }
    __syncthreads();
    if (k0 + 32 < 256) {
      // issue next A loads after the vmcnt(0) drain; latency hides under MFMA
#pragma unroll
      for (int j = 0; j < 2; ++j) {
        ra[j][0] = *(const float4*)(gAf[j] + k0 + 32);
        ra[j][1] = *(const float4*)(gAf[j] + k0 + 36);
      }
    }
    bfv8 a[4], b[4];
#pragma unroll
    for (int m = 0; m < 4; ++m)
      a[m] = *(const bfv8*)&As[(wm + m * 16 + fr) * 32 + sw];
#pragma unroll
    for (int n = 0; n < 4; ++n)
      b[n] = *(const bfv8*)&Bs[(wn + n * 16 + fr) * 32 + sw];
#pragma unroll
    for (int m = 0; m < 4; ++m)
#pragma unroll
      for (int n = 0; n < 4; ++n)
        acc[m][n] = __builtin_amdgcn_mfma_f32_16x16x32_bf16(a[m], b[n], acc[m][n], 0, 0, 0);
    __syncthreads();
  }

  const int row0 = (lane >> 4) * 4;
  const int col = lane & 15;
#pragma unroll
  for (int m = 0; m < 4; ++m) {
#pragma unroll
    for (int n = 0; n < 4; ++n) {
      int cn = bn + wn + n * 16 + col;
      float bv = bias[cn];
#pragma unroll
      for (int j = 0; j < 4; ++j) {
        int mg = bm + wm + m * 16 + row0 + j;
        if (mg < M)
          C[(size_t)mg * 256 + cn] = f2b(acc[m][n][j] + bv);
      }
    }
  }
}

// ---------------------------------------------------------------------------
// MFMA GEMM, m97-style gload_lds staging, BM templated (128 or 64), BN=128.
// AMODE 0: plain rows. 2: m=b*1800+lq -> token map row.
// OUTMODE: 0 = f32, 1 = bf16, 2 = bf16 + relu.
// ---------------------------------------------------------------------------
template<int AMODE, int OUTMODE, int BM>
__global__ __launch_bounds__(256) void gemm_mfma(
    const ushort* __restrict__ A, const ushort* __restrict__ W,
    const float* __restrict__ bias, void* __restrict__ Cv,
    int M, int N, int K) {
  constexpr int AJ = BM / 64;
  constexpr int MR = BM / 32;
  __shared__ ushort As[BM * 32];
  __shared__ ushort Bs[128 * 32];
  const int tid = threadIdx.x;
  const int bm = blockIdx.y * BM, bn = blockIdx.x * 128;
  const int wave = tid >> 6, lane = tid & 63;

  const int srow = wave * 16 + (lane >> 2);
  const ushort* gA[AJ]; ushort* lA[AJ];
  const ushort* gB[2];  ushort* lB[2];
#pragma unroll
  for (int j = 0; j < AJ; ++j) {
    int row = j * 64 + srow;
    int gch = (lane & 3) ^ (row & 3);
    int gm = bm + row; if (gm >= M) gm = M - 1;
    int asrc;
    if (AMODE == 0) {
      asrc = gm;
    } else {
      int b = gm / LQ_, lq = gm - b * LQ_;
      int qq = lq / NK_, kk = lq - qq * NK_;
      asrc = qq * (BS_ * NK_) + b * NK_ + kk;
    }
    gA[j] = A + (size_t)asrc * K + gch * 8;
    lA[j] = As + (j * 4 + wave) * 512;
  }
#pragma unroll
  for (int j = 0; j < 2; ++j) {
    int row = j * 64 + srow;
    int gch = (lane & 3) ^ (row & 3);
    gB[j] = W + (size_t)(bn + row) * K + gch * 8;
    lB[j] = Bs + (j * 4 + wave) * 512;
  }

  const int wm = (wave >> 1) * (BM / 2), wn = (wave & 1) * 64;
  const int fr = lane & 15, fk = lane >> 4;
  const int sw = (fk ^ (fr & 3)) << 3;

  f32x4 acc[MR][4] = {};
  for (int k0 = 0; k0 < K; k0 += 32) {
#pragma unroll
    for (int j = 0; j < AJ; ++j) gload16(gA[j] + k0, lA[j]);
#pragma unroll
    for (int j = 0; j < 2; ++j) gload16(gB[j] + k0, lB[j]);
    __syncthreads();
    bfv8 a[MR], b[4];
#pragma unroll
    for (int m = 0; m < MR; ++m)
      a[m] = *(const bfv8*)&As[(wm + m * 16 + fr) * 32 + sw];
#pragma unroll
    for (int n = 0; n < 4; ++n)
      b[n] = *(const bfv8*)&Bs[(wn + n * 16 + fr) * 32 + sw];
#pragma unroll
    for (int m = 0; m < MR; ++m)
#pragma unroll
      for (int n = 0; n < 4; ++n)
        acc[m][n] = __builtin_amdgcn_mfma_f32_16x16x32_bf16(a[m], b[n], acc[m][n], 0, 0, 0);
    __syncthreads();
  }

  const int row0 = (lane >> 4) * 4;
  const int col = lane & 15;
#pragma unroll
  for (int m = 0; m < MR; ++m) {
#pragma unroll
    for (int n = 0; n < 4; ++n) {
      int cn = bn + wn + n * 16 + col;
      float bv = bias[cn];
#pragma unroll
      for (int j = 0; j < 4; ++j) {
        int mg = bm + wm + m * 16 + row0 + j;
        if (mg < M) {
          float o = acc[m][n][j] + bv;
          if (OUTMODE == 2) o = fmaxf(o, 0.f);
          if (OUTMODE == 0) ((float*)Cv)[(size_t)mg * N + cn] = o;
          else ((ushort*)Cv)[(size_t)mg * N + cn] = f2b(o);
        }
      }
    }
  }
}

// ---------------------------------------------------------------------------
// Fused GEMM (N=256) + residual + LayerNorm epilogue (BM=32, bf16 residual).
// LNMODE: 0 = bf16 out + POS, 1 = bf16 out, 2 = f32 out.
// ---------------------------------------------------------------------------
template<int LNMODE>
__global__ __launch_bounds__(256) void gemm_ln(
    const ushort* __restrict__ A, const ushort* __restrict__ W,
    const float* __restrict__ bias, const ushort* __restrict__ Xb,
    const float* __restrict__ POS, const float* __restrict__ G,
    const float* __restrict__ Bb, void* __restrict__ Out, int K) {
  __shared__ float Ep[32][264];              // 33.8 KB; staging aliased below
  ushort* As = (ushort*)&Ep[0][0];           // 32x32  = 2 KB
  ushort* Bs = As + 32 * 32;                 // 256x32 = 16 KB

  const int tid = threadIdx.x;
  const int wave = tid >> 6, lane = tid & 63;
  const int bm = blockIdx.x * 32;

  const int arow = wave * 8 + (lane >> 2);
  const int agch = (lane & 3) ^ (arow & 3);
  const ushort* gA = A + (size_t)(bm + arow) * K + agch * 8;
  ushort* lA = As + wave * 256;
  const int srow = wave * 16 + (lane >> 2);
  const ushort* gB[4]; ushort* lB[4];
#pragma unroll
  for (int j = 0; j < 4; ++j) {
    int row = j * 64 + srow;
    int gch = (lane & 3) ^ (row & 3);
    gB[j] = W + (size_t)row * K + gch * 8;
    lB[j] = Bs + (j * 4 + wave) * 512;
  }

  const int wn = wave * 64;
  const int fr = lane & 15, fk = lane >> 4;
  const int sw = (fk ^ (fr & 3)) << 3;

  f32x4 acc[2][4] = {};
  for (int k0 = 0; k0 < K; k0 += 32) {
    if (lane < 32) gload16(gA + k0, lA);
#pragma unroll
    for (int j = 0; j < 4; ++j) gload16(gB[j] + k0, lB[j]);
    __syncthreads();
    bfv8 a[2], b[4];
#pragma unroll
    for (int m = 0; m < 2; ++m)
      a[m] = *(const bfv8*)&As[(m * 16 + fr) * 32 + sw];
#pragma unroll
    for (int n = 0; n < 4; ++n)
      b[n] = *(const bfv8*)&Bs[(wn + n * 16 + fr) * 32 + sw];
#pragma unroll
    for (int m = 0; m < 2; ++m)
#pragma unroll
      for (int n = 0; n < 4; ++n)
        acc[m][n] = __builtin_amdgcn_mfma_f32_16x16x32_bf16(a[m], b[n], acc[m][n], 0, 0, 0);
    __syncthreads();
  }

  const int row0 = (lane >> 4) * 4;
  const int col = lane & 15;
  float bv[4];
#pragma unroll
  for (int n = 0; n < 4; ++n) bv[n] = bias[wn + n * 16 + col];

  const float4 g4 = *(const float4*)(G + lane * 4);
  const float4 bb4 = *(const float4*)(Bb + lane * 4);

#pragma unroll
  for (int m = 0; m < 2; ++m)
#pragma unroll
    for (int n = 0; n < 4; ++n)
#pragma unroll
      for (int j = 0; j < 4; ++j)
        Ep[m * 16 + row0 + j][wn + n * 16 + col] = acc[m][n][j] + bv[n];
  __syncthreads();

  for (int rr = 0; rr < 8; ++rr) {
    int lrow = wave * 8 + rr;
    size_t off = (size_t)(bm + lrow) * 256 + lane * 4;
    float4 ev = *(const float4*)&Ep[lrow][lane * 4];
    ushort4 x4 = *(const ushort4*)(Xb + off);
    float4 v = make_float4(b2f(x4.x) + ev.x, b2f(x4.y) + ev.y,
                           b2f(x4.z) + ev.z, b2f(x4.w) + ev.w);
    float s = v.x + v.y + v.z + v.w;
#pragma unroll
    for (int o = 32; o; o >>= 1) s += __shfl_xor(s, o);
    float mu = s * (1.0f / 256.0f);
    float4 c = make_float4(v.x - mu, v.y - mu, v.z - mu, v.w - mu);
    float q = c.x * c.x + c.y * c.y + c.z * c.z + c.w * c.w;
#pragma unroll
    for (int o = 32; o; o >>= 1) q += __shfl_xor(q, o);
    float rs = rsqrtf(q * (1.0f / 256.0f) + 1e-5f);
    float4 o4;
    o4.x = c.x * rs * g4.x + bb4.x;
    o4.y = c.y * rs * g4.y + bb4.y;
    o4.z = c.z * rs * g4.z + bb4.z;
    o4.w = c.w * rs * g4.w + bb4.w;
    if (LNMODE == 0) {
      float4 pv = *(const float4*)(POS + off);
      o4.x += pv.x; o4.y += pv.y; o4.z += pv.z; o4.w += pv.w;
    }
    if (LNMODE == 2) {
      *(float4*)((float*)Out + off) = o4;
    } else {
      ushort4 ob;
      ob.x = f2b(o4.x); ob.y = f2b(o4.y); ob.z = f2b(o4.z); ob.w = f2b(o4.w);
      *(ushort4*)((ushort*)Out + off) = ob;
    }
  }
}

// ---------------------------------------------------------------------------
// Across-attention via MFMA (unchanged, known-good).
// ---------------------------------------------------------------------------
__global__ __launch_bounds__(256) void attn_across_mfma(
    const ushort* __restrict__ QKV, ushort* __restrict__ O) {
  __shared__ ushort Qs[112][40];
  __shared__ ushort Ks[112][40];
  __shared__ ushort Vt[32][136];
  __shared__ ushort Ps[112][136];
  const int b = blockIdx.x >> 3, h = blockIdx.x & 7;
  const int tid = threadIdx.x;

  for (int idx = tid; idx < 112 * 16; idx += 256) {
    int r = idx >> 4, du = (idx & 15) * 2;
    uint q = 0, k = 0;
    if (r < 100) {
      size_t base = ((size_t)r * 144 + b) * 768 + h * 32 + du;
      q = *(const uint*)(QKV + base);
      k = *(const uint*)(QKV + base + 256);
    }
    *(uint*)&Qs[r][du] = q;
    *(uint*)&Ks[r][du] = k;
  }
  for (int idx = tid; idx < 128 * 32; idx += 256) {
    int s = idx >> 5, d = idx & 31;
    ushort v = 0;
    if (s < 100) v = QKV[((size_t)s * 144 + b) * 768 + 512 + h * 32 + d];
    Vt[d][s] = v;
  }
  for (int idx = tid; idx < 112 * 8; idx += 256) {
    int r = idx >> 3, c = 112 + (idx & 7) * 2;
    *(uint*)&Ps[r][c] = 0;
  }
  __syncthreads();

  const int wave = tid >> 6, lane = tid & 63;
  const int fr = lane & 15, fk = lane >> 4;
  const float scale = 0.17677669529663687f;

#pragma unroll
  for (int mi = 0; mi < 2; ++mi) {
    const int mt = wave + mi * 4;
    if (mt < 7) {
      bfv8 aq = *(const bfv8*)&Qs[mt * 16 + fr][fk * 8];
      f32x4 sacc[7];
#pragma unroll
      for (int nt = 0; nt < 7; ++nt) {
        bfv8 bk = *(const bfv8*)&Ks[nt * 16 + fr][fk * 8];
        f32x4 z = {0.f, 0.f, 0.f, 0.f};
        sacc[nt] = __builtin_amdgcn_mfma_f32_16x16x32_bf16(aq, bk, z, 0, 0, 0);
      }
      const bool maskc = (lane & 15) >= 4;
#pragma unroll
      for (int j = 0; j < 4; ++j) {
        float v[7];
        float mx = -1e30f;
#pragma unroll
        for (int nt = 0; nt < 7; ++nt) {
          float s = sacc[nt][j] * scale;
          if (nt == 6 && maskc) s = -1e30f;
          v[nt] = s;
          mx = fmaxf(mx, s);
        }
        mx = fmaxf(mx, __shfl_xor(mx, 1));
        mx = fmaxf(mx, __shfl_xor(mx, 2));
        mx = fmaxf(mx, __shfl_xor(mx, 4));
        mx = fmaxf(mx, __shfl_xor(mx, 8));
        float sum = 0.f;
#pragma unroll
        for (int nt = 0; nt < 7; ++nt) {
          v[nt] = __expf(v[nt] - mx);
          sum += v[nt];
        }
        sum += __shfl_xor(sum, 1);
        sum += __shfl_xor(sum, 2);
        sum += __shfl_xor(sum, 4);
        sum += __shfl_xor(sum, 8);
        float inv = 1.f / sum;
        int row = mt * 16 + (lane >> 4) * 4 + j;
#pragma unroll
        for (int nt = 0; nt < 7; ++nt)
          Ps[row][nt * 16 + (lane & 15)] = f2b(v[nt] * inv);
      }
    }
  }
  __syncthreads();

  f32x4 oacc[2][2] = {};
#pragma unroll
  for (int mi = 0; mi < 2; ++mi) {
    const int mt = wave + mi * 4;
    if (mt < 7) {
#pragma unroll
      for (int ks = 0; ks < 4; ++ks) {
        bfv8 ap = *(const bfv8*)&Ps[mt * 16 + fr][ks * 32 + fk * 8];
#pragma unroll
        for (int n = 0; n < 2; ++n) {
          bfv8 bv = *(const bfv8*)&Vt[n * 16 + fr][ks * 32 + fk * 8];
          oacc[mi][n] = __builtin_amdgcn_mfma_f32_16x16x32_bf16(ap, bv, oacc[mi][n], 0, 0, 0);
        }
      }
#pragma unroll
      for (int n = 0; n < 2; ++n) {
#pragma unroll
        for (int j = 0; j < 4; ++j) {
          int q = mt * 16 + (lane >> 4) * 4 + j;
          if (q < 100) {
            O[((size_t)q * 144 + b) * 256 + h * 32 + n * 16 + (lane & 15)] =
                f2b(oacc[mi][n][j]);
          }
        }
      }
    }
  }
}

// ---------------------------------------------------------------------------
// Within-attention (unchanged, known-good).
// ---------------------------------------------------------------------------
__global__ __launch_bounds__(256) void attn_within(
    const ushort* __restrict__ QKV, ushort* __restrict__ O) {
  constexpr int ST = 258;
  __shared__ ushort Qs[18 * ST];
  __shared__ ushort Ks[18 * ST];
  __shared__ ushort Vs[18 * ST];
  const int bidx = blockIdx.x;
  const int qq = bidx >> 3, bb = bidx & 7;
  const int tid = threadIdx.x;
  for (int idx = tid; idx < 18 * 128; idx += 256) {
    int r = idx >> 7, j2 = (idx & 127) * 2;
    size_t base = ((size_t)qq * 144 + bb * 18 + r) * 768 + j2;
    *(uint*)&Qs[r * ST + j2] = *(const uint*)(QKV + base);
    *(uint*)&Ks[r * ST + j2] = *(const uint*)(QKV + base + 256);
    *(uint*)&Vs[r * ST + j2] = *(const uint*)(QKV + base + 512);
  }
  __syncthreads();
  const int wave = tid >> 6, lane = tid & 63;
  const int h = wave * 2 + (lane >> 5);
  const int li = lane & 31;
  const int hd = h * 32;
  const float scale = 0.17677669529663687f;
  const bool kv = li < 18;
  for (int s = 0; s < 18; ++s) {
    float sc = 0.f;
    if (kv) {
      const ushort* qrow = &Qs[s * ST + hd];
      const ushort* krow = &Ks[li * ST + hd];
#pragma unroll 8
      for (int d = 0; d < 32; ++d) sc += b2f(qrow[d]) * b2f(krow[d]);
    }
    sc = kv ? sc * scale : -1e30f;
    float mx = sc;
    mx = fmaxf(mx, __shfl_xor(mx, 16));
    mx = fmaxf(mx, __shfl_xor(mx, 8));
    mx = fmaxf(mx, __shfl_xor(mx, 4));
    mx = fmaxf(mx, __shfl_xor(mx, 2));
    mx = fmaxf(mx, __shfl_xor(mx, 1));
    float e = kv ? __expf(sc - mx) : 0.f;
    float sum = e;
    sum += __shfl_xor(sum, 16);
    sum += __shfl_xor(sum, 8);
    sum += __shfl_xor(sum, 4);
    sum += __shfl_xor(sum, 2);
    sum += __shfl_xor(sum, 1);
    float p = e / sum;
    float o = 0.f;
    const int half = lane & 32;
#pragma unroll
    for (int k = 0; k < 18; ++k) {
      float pk = __shfl(p, half + k);
      o += pk * b2f(Vs[k * ST + hd + li]);
    }
    O[((size_t)qq * 144 + bb * 18 + s) * 256 + hd + li] = f2b(o);
  }
}

// ---------------------------------------------------------------------------
// Deformable sampling, two-phase (unchanged, known-good).
// ---------------------------------------------------------------------------
__global__ __launch_bounds__(256) void deform_sample(
    const float* __restrict__ OFFAW, const ushort* __restrict__ V,
    const float* __restrict__ REF, ushort* __restrict__ OUT) {
  __shared__ uint2 sDesc[32 * 65];
  const int tid = threadIdx.x;
  const int m0 = blockIdx.x * 4;

  const int WH[4] = {100, 50, 25, 13};
  const int STl[4] = {0, 10000, 12500, 13125};

#pragma unroll
  for (int dd = 0; dd < 2; ++dd) {
    const int desc = tid + dd * 256;
    const int g = desc >> 7, rem = desc & 127;
    const int h = rem >> 4, lp = rem & 15, li = lp >> 2, p = lp & 3;
    const int m = m0 + g;
    const int b = m / LQ_, lq = m - b * LQ_;

    float awv = OFFAW[(size_t)m * 384 + 256 + h * 16 + lp];
    float mx = awv;
    mx = fmaxf(mx, __shfl_xor(mx, 8, 16));
    mx = fmaxf(mx, __shfl_xor(mx, 4, 16));
    mx = fmaxf(mx, __shfl_xor(mx, 2, 16));
    mx = fmaxf(mx, __shfl_xor(mx, 1, 16));
    float e = __expf(awv - mx);
    float sm = e;
    sm += __shfl_xor(sm, 8, 16);
    sm += __shfl_xor(sm, 4, 16);
    sm += __shfl_xor(sm, 2, 16);
    sm += __shfl_xor(sm, 1, 16);
    const float aw = e / sm;

    const float* offp = OFFAW + (size_t)m * 384 + h * 32 + li * 8 + p * 2;
    const float ox = offp[0], oy = offp[1];
    const float rx = REF[(((size_t)lq * 8 + b) * 4 + li) * 2 + 0];
    const float ry = REF[(((size_t)lq * 8 + b) * 4 + li) * 2 + 1];
    const int Wl = WH[li], st = STl[li];
    const float fW = (float)Wl;
    const float x = fmaf(rx, fW, ox) - 0.5f;
    const float y = fmaf(ry, fW, oy) - 0.5f;
    const float x0f = floorf(x), y0f = floorf(y);
    const float lx = x - x0f, ly = y - y0f;
    const int x0 = (int)x0f, y0 = (int)y0f;
    const int base = (g * 8 + h) * 65 + lp * 4;
#pragma unroll
    for (int c = 0; c < 4; ++c) {
      const int cx = c & 1, cy = c >> 1;
      const int xi = x0 + cx, yi = y0 + cy;
      const bool va = (xi >= 0) && (xi < Wl) && (yi >= 0) && (yi < Wl);
      const int xc = min(max(xi, 0), Wl - 1);
      const int yc = min(max(yi, 0), Wl - 1);
      const float wx = cx ? lx : (1.f - lx);
      const float wy = cy ? ly : (1.f - ly);
      const float wgt = va ? aw * wx * wy : 0.f;
      uint2 dv;
      dv.x = (uint)(st + yc * Wl + xc);
      dv.y = __builtin_bit_cast(uint, wgt);
      sDesc[base + c] = dv;
    }
  }
  __syncthreads();

  const int g = tid >> 6;
  const int h = (tid >> 3) & 7;
  const int d4 = (tid & 7) * 4;
  const int m = m0 + g;
  const int b = m / LQ_, lq = m - b * LQ_;
  const int qq = lq / NK_, kk = lq - qq * NK_;
  const ushort* Vg = V + ((size_t)b * LIN_) * 256 + h * 32 + d4;
  const int dbase = (g * 8 + h) * 65;
  float a0 = 0.f, a1 = 0.f, a2 = 0.f, a3 = 0.f;
#pragma unroll
  for (int lp = 0; lp < 16; ++lp) {
#pragma unroll
    for (int c = 0; c < 4; ++c) {
      const uint2 dv = sDesc[dbase + lp * 4 + c];
      const float w = __builtin_bit_cast(float, dv.y);
      const ushort4 v = *(const ushort4*)(Vg + (size_t)dv.x * 256);
      a0 = fmaf(w, b2f(v.x), a0);
      a1 = fmaf(w, b2f(v.y), a1);
      a2 = fmaf(w, b2f(v.z), a2);
      a3 = fmaf(w, b2f(v.w), a3);
    }
  }
  const size_t tok = (size_t)qq * 144 + b * 18 + kk;
  ushort4 o;
  o.x = f2b(a0); o.y = f2b(a1); o.z = f2b(a2); o.w = f2b(a3);
  *(ushort4*)(OUT + tok * 256 + h * 32 + d4) = o;
}

// ---------------------------------------------------------------------------
extern "C" void kernel_launch(void* const* d_in, const int* in_sizes, int n_in,
                              void* d_out, int out_size, void* d_ws, size_t ws_size,
                              hipStream_t stream) {
  const float* tgt  = (const float*)d_in[0];
  const float* pos  = (const float*)d_in[1];
  const float* ref  = (const float*)d_in[2];
  const float* mem  = (const float*)d_in[3];
  const float* across_in_w  = (const float*)d_in[4];
  const float* across_in_b  = (const float*)d_in[5];
  const float* across_out_w = (const float*)d_in[6];
  const float* across_out_b = (const float*)d_in[7];
  const float* within_in_w  = (const float*)d_in[8];
  const float* within_in_b  = (const float*)d_in[9];
  const float* within_out_w = (const float*)d_in[10];
  const float* within_out_b = (const float*)d_in[11];
  const float* off_w  = (const float*)d_in[12];
  const float* off_b  = (const float*)d_in[13];
  const float* aw_w   = (const float*)d_in[14];
  const float* aw_b   = (const float*)d_in[15];
  const float* val_w  = (const float*)d_in[16];
  const float* val_b  = (const float*)d_in[17];
  const float* msout_w = (const float*)d_in[18];
  const float* msout_b = (const float*)d_in[19];
  const float* lin1_w  = (const float*)d_in[20];
  const float* lin1_b  = (const float*)d_in[21];
  const float* lin2_w  = (const float*)d_in[22];
  const float* lin2_b  = (const float*)d_in[23];
  const float* lin1p_w = (const float*)d_in[24];
  const float* lin1p_b = (const float*)d_in[25];
  const float* lin2p_w = (const float*)d_in[26];
  const float* lin2p_b = (const float*)d_in[27];
  const float* across_norm_g = (const float*)d_in[28];
  const float* across_norm_b = (const float*)d_in[29];
  const float* within_norm_g = (const float*)d_in[30];
  const float* within_norm_b = (const float*)d_in[31];
  const float* norm1_g = (const float*)d_in[32];
  const float* norm1_b = (const float*)d_in[33];
  const float* norm2_g = (const float*)d_in[34];
  const float* norm2_b = (const float*)d_in[35];
  const float* norm2p_g = (const float*)d_in[36];
  const float* norm2p_b = (const float*)d_in[37];

  // ---- workspace layout (QKVb/R1 and tgtb/OFFAW share) ----
  char* w = (char*)d_ws;
  ushort* Wb    = (ushort*)w;  w += 3604480;                         // weights bf16
  ushort* QKVb  = (ushort*)w;  w += (size_t)(BS_ * LIN_) * 256 * 2;  // 54.5MB region (QKV uses 22.1MB)
  ushort* AOb   = (ushort*)w;  w += (size_t)T_ * 256 * 2;            // 7.37MB (also SMPb)
  ushort* CTb   = (ushort*)w;  w += (size_t)T_ * 256 * 2;            // 7.37MB (bf16 residual stream)
  ushort* Vb    = (ushort*)w;  w += (size_t)(BS_ * LIN_) * 256 * 2;  // 54.5MB (also Uff)
  float*  R2    = (float*)w;   w += (size_t)T_ * 384 * 4;            // 22.1MB: tgtb then OFFAW
  float*  OAB   = (float*)w;   w += 384 * 4;
  ushort* tgtb  = (ushort*)R2;
  float*  OFFAW = R2;       // written after tgtb's last use (step 5; tgtb last read in step 4)
  ushort* Uff   = Vb;
  ushort* SMPb  = AOb;

  ushort* W_across_in  = Wb + WOF0;
  ushort* W_within_in  = Wb + WOF1;
  ushort* W_across_out = Wb + WOF2;
  ushort* W_within_out = Wb + WOF3;
  ushort* W_offaw      = Wb + WOF4;   // off rows 0..255, aw rows 256..383
  ushort* W_val        = Wb + WOF6;
  ushort* W_msout      = Wb + WOF7;
  ushort* W_lin1       = Wb + WOF8;
  ushort* W_lin2       = Wb + WOF9;
  ushort* W_lin1p      = Wb + WOF10;
  ushort* W_lin2p      = Wb + WOF11;

  dim3 blk(256);
  const int MT = T_;                 // 14400
  const int MV = BS_ * LIN_;         // 106352
  const int MVt = (MV + 127) / 128;  // 831 (BM=128 vproj grid)
  const int MT64 = MT / 64;          // 225 (BM=64 GEMM grid)
  const int MT32 = MT / 32;          // 450 (gemm_ln grid)

  // 0. conversions (weights+bias fused; tgt only — mem is read directly)
  conv_weights<<<dim3((WTOT / 8 + 255) / 256), blk, 0, stream>>>(
      across_in_w, within_in_w, across_out_w, within_out_w, off_w, aw_w,
      val_w, msout_w, lin1_w, lin2_w, lin1p_w, lin2p_w, Wb, off_b, aw_b, OAB);
  conv_tgt<<<dim3(MT * 32 / 256), blk, 0, stream>>>(tgt, tgtb);
  // 1. value projection (mem f32 direct, A-pipelined) -> Vb
  gemm_vproj<<<dim3(2, MVt), blk, 0, stream>>>(
      mem, W_val, val_b, Vb, MV);
  // 2. across in-proj -> QKVb
  gemm_mfma<0, 1, 64><<<dim3(6, MT64), blk, 0, stream>>>(
      tgtb, W_across_in, across_in_b, QKVb, MT, 768, 256);
  // 3. across attention -> AOb
  attn_across_mfma<<<dim3(144 * 8), blk, 0, stream>>>(QKVb, AOb);
  // 4. across out-proj + LN(tgtb + .) + pos -> CTb (bf16)
  gemm_ln<0><<<dim3(MT32), blk, 0, stream>>>(
      AOb, W_across_out, across_out_b, tgtb, pos,
      across_norm_g, across_norm_b, CTb, 256);
  // 5. fused off+aw (token map) -> OFFAW (overwrites tgtb; tgtb dead)
  gemm_mfma<2, 0, 64><<<dim3(3, MT64), blk, 0, stream>>>(
      CTb, W_offaw, OAB, OFFAW, MT, 384, 256);
  // 6. bilinear sampling -> SMPb
  deform_sample<<<dim3(T_ / 4), blk, 0, stream>>>(OFFAW, Vb, ref, SMPb);
  // 7. msout + norm1(CTb + .) -> CTb (in-place, block-local safe)
  gemm_ln<1><<<dim3(MT32), blk, 0, stream>>>(
      SMPb, W_msout, msout_b, CTb, nullptr,
      norm1_g, norm1_b, CTb, 256);
  // 8. lin1 (+relu) -> Uff
  gemm_mfma<0, 2, 64><<<dim3(8, MT64), blk, 0, stream>>>(
      CTb, W_lin1, lin1_b, Uff, MT, 1024, 256);
  // 9. lin2 + norm2(CTb + .) + pos -> CTb
  gemm_ln<0><<<dim3(MT32), blk, 0, stream>>>(
      Uff, W_lin2, lin2_b, CTb, pos,
      norm2_g, norm2_b, CTb, 1024);
  // 10. within in-proj -> QKVb
  gemm_mfma<0, 1, 64><<<dim3(6, MT64), blk, 0, stream>>>(
      CTb, W_within_in, within_in_b, QKVb, MT, 768, 256);
  // 11. within attention -> AOb
  attn_within<<<dim3(NQ_ * BS_), blk, 0, stream>>>(QKVb, AOb);
  // 12. within out-proj + within_norm(CTb + .) -> CTb
  gemm_ln<1><<<dim3(MT32), blk, 0, stream>>>(
      AOb, W_within_out, within_out_b, CTb, nullptr,
      within_norm_g, within_norm_b, CTb, 256);
  // 13. lin1p (+relu) -> Uff
  gemm_mfma<0, 2, 64><<<dim3(8, MT64), blk, 0, stream>>>(
      CTb, W_lin1p, lin1p_b, Uff, MT, 1024, 256);
  // 14. lin2p + norm2p(CTb + .) -> d_out (f32)
  gemm_ln<2><<<dim3(MT32), blk, 0, stream>>>(
      Uff, W_lin2p, lin2p_b, CTb, nullptr,
      norm2p_g, norm2p_b, (float*)d_out, 1024);
}

// Round 23
// 374.581 us; speedup vs baseline: 1.0062x; 1.0044x over previous
//
#include <hip/hip_runtime.h>
#include <cstdint>
#include <cstddef>

constexpr int D_   = 256;
constexpr int NK_  = 18;
constexpr int NQ_  = 100;
constexpr int BS_  = 8;
constexpr int T_   = NQ_ * BS_ * NK_;   // 14400 tokens
constexpr int LIN_ = 13294;
constexpr int LQ_  = NQ_ * NK_;         // 1800

typedef __attribute__((ext_vector_type(8))) short bfv8;
typedef __attribute__((ext_vector_type(4))) float f32x4;

__device__ __forceinline__ ushort f2b(float f) {
  uint32_t u = __builtin_bit_cast(uint32_t, f);
  u += 0x7fffu + ((u >> 16) & 1u);
  return (ushort)(u >> 16);
}
__device__ __forceinline__ float b2f(ushort h) {
  uint32_t u = ((uint32_t)h) << 16;
  return __builtin_bit_cast(float, u);
}
__device__ __forceinline__ uint pk2(float lo, float hi) {
  return (uint)f2b(lo) | ((uint)f2b(hi) << 16);
}
// async global -> LDS, 16B per lane; lds base must be wave-uniform.
__device__ __forceinline__ void gload16(const ushort* g, ushort* l) {
  __builtin_amdgcn_global_load_lds(
      (const __attribute__((address_space(1))) void*)g,
      (__attribute__((address_space(3))) void*)l, 16, 0, 0);
}

// ---------------------------------------------------------------------------
// Weight conversion arena offsets (off_w + aw_w adjacent -> fused N=384).
// ---------------------------------------------------------------------------
constexpr int WOF0  = 0;        // across_in_w 196608
constexpr int WOF1  = 196608;   // within_in_w 196608
constexpr int WOF2  = 393216;   // across_out_w 65536
constexpr int WOF3  = 458752;   // within_out_w 65536
constexpr int WOF4  = 524288;   // off_w 65536
constexpr int WOF5  = 589824;   // aw_w 32768
constexpr int WOF6  = 622592;   // val_w 65536
constexpr int WOF7  = 688128;   // msout_w 65536
constexpr int WOF8  = 753664;   // lin1_w 262144
constexpr int WOF9  = 1015808;  // lin2_w 262144
constexpr int WOF10 = 1277952;  // lin1p_w 262144
constexpr int WOF11 = 1540096;  // lin2p_w 262144
constexpr int WTOT  = 1802240;

// Weights f32->bf16; block 0 additionally packs the fused off/aw bias.
__global__ __launch_bounds__(256) void conv_weights(
    const float* __restrict__ w0, const float* __restrict__ w1,
    const float* __restrict__ w2, const float* __restrict__ w3,
    const float* __restrict__ w4, const float* __restrict__ w5,
    const float* __restrict__ w6, const float* __restrict__ w7,
    const float* __restrict__ w8, const float* __restrict__ w9,
    const float* __restrict__ w10, const float* __restrict__ w11,
    ushort* __restrict__ out,
    const float* __restrict__ off_b, const float* __restrict__ aw_b,
    float* __restrict__ oab) {
  if (blockIdx.x == 0) {
    int t = threadIdx.x;
    oab[t] = (t < 256) ? off_b[t] : aw_b[t - 256];
    oab[t + 128] = (t + 128 < 256) ? off_b[t + 128] : aw_b[t - 128];
  }
  int i8 = (blockIdx.x * 256 + threadIdx.x) * 8;
  if (i8 >= WTOT) return;
  const float* src; int off;
  if      (i8 < WOF1)  { src = w0;  off = WOF0; }
  else if (i8 < WOF2)  { src = w1;  off = WOF1; }
  else if (i8 < WOF3)  { src = w2;  off = WOF2; }
  else if (i8 < WOF4)  { src = w3;  off = WOF3; }
  else if (i8 < WOF5)  { src = w4;  off = WOF4; }
  else if (i8 < WOF6)  { src = w5;  off = WOF5; }
  else if (i8 < WOF7)  { src = w6;  off = WOF6; }
  else if (i8 < WOF8)  { src = w7;  off = WOF7; }
  else if (i8 < WOF9)  { src = w8;  off = WOF8; }
  else if (i8 < WOF10) { src = w9;  off = WOF9; }
  else if (i8 < WOF11) { src = w10; off = WOF10; }
  else                 { src = w11; off = WOF11; }
  const float4 v0 = *(const float4*)(src + (i8 - off));
  const float4 v1 = *(const float4*)(src + (i8 - off) + 4);
  uint4 o;
  o.x = pk2(v0.x, v0.y); o.y = pk2(v0.z, v0.w);
  o.z = pk2(v1.x, v1.y); o.w = pk2(v1.z, v1.w);
  *(uint4*)(out + i8) = o;
}

// ---------------------------------------------------------------------------
// tgt f32 -> bf16 (mem is consumed directly by gemm_vproj).
// ---------------------------------------------------------------------------
__global__ __launch_bounds__(256) void conv_tgt(
    const float* __restrict__ tgt, ushort* __restrict__ tgtb) {
  int idx = blockIdx.x * 256 + threadIdx.x;
  int r = idx >> 5, c = (idx & 31) * 8;
  if (r >= T_) return;
  const float* p = tgt + (size_t)r * 256 + c;
  float4 v0 = *(const float4*)p, v1 = *(const float4*)(p + 4);
  uint4 o;
  o.x = pk2(v0.x, v0.y); o.y = pk2(v0.z, v0.w);
  o.z = pk2(v1.x, v1.y); o.w = pk2(v1.z, v1.w);
  *(uint4*)(tgtb + (size_t)r * 256 + c) = o;
}

// ---------------------------------------------------------------------------
// Value projection reading mem f32 directly (reorder folded into A-row map;
// f32->bf16 in A staging).  A registers single-depth pipelined.  B on
// global_load_lds.  2-barrier BM=128/BN=128 loop (best-measured config).
// ---------------------------------------------------------------------------
__global__ __launch_bounds__(256) void gemm_vproj(
    const float* __restrict__ Amem, const ushort* __restrict__ W,
    const float* __restrict__ bias, ushort* __restrict__ C, int M) {
  __shared__ ushort As[128 * 32];
  __shared__ ushort Bs[128 * 32];
  const int tid = threadIdx.x;
  const int bm = blockIdx.y * 128, bn = blockIdx.x * 128;
  const int wave = tid >> 6, lane = tid & 63;

  const int srow = wave * 16 + (lane >> 2);
  const float* gAf[2]; ushort* lA[2];
  const ushort* gB[2]; ushort* lB[2];
#pragma unroll
  for (int j = 0; j < 2; ++j) {
    int row = j * 64 + srow;
    int gch = (lane & 3) ^ (row & 3);
    int gm = bm + row; if (gm >= M) gm = M - 1;
    int b = gm / LIN_, i = gm - b * LIN_;       // output row b*LIN+i
    gAf[j] = Amem + ((size_t)i * BS_ + b) * 256 + gch * 8;  // mem row i*8+b
    lA[j] = As + (j * 4 + wave) * 512 + lane * 8;           // per-lane 16B slot
    gB[j] = W + (size_t)(bn + row) * 256 + gch * 8;
    lB[j] = Bs + (j * 4 + wave) * 512;
  }

  const int wm = (wave >> 1) * 64, wn = (wave & 1) * 64;
  const int fr = lane & 15, fk = lane >> 4;
  const int sw = (fk ^ (fr & 3)) << 3;

  float4 ra[2][2];   // pipelined A registers (2 rows x 8 floats)
#pragma unroll
  for (int j = 0; j < 2; ++j) {
    ra[j][0] = *(const float4*)(gAf[j]);
    ra[j][1] = *(const float4*)(gAf[j] + 4);
  }

  f32x4 acc[4][4] = {};
  for (int k0 = 0; k0 < 256; k0 += 32) {
#pragma unroll
    for (int j = 0; j < 2; ++j) gload16(gB[j] + k0, lB[j]);
#pragma unroll
    for (int j = 0; j < 2; ++j) {
      uint4 o;
      o.x = pk2(ra[j][0].x, ra[j][0].y); o.y = pk2(ra[j][0].z, ra[j][0].w);
      o.z = pk2(ra[j][1].x, ra[j][1].y); o.w = pk2(ra[j][1].z, ra[j][1].w);
      *(uint4*)lA[j] = o;
    }
    __syncthreads();
    if (k0 + 32 < 256) {
#pragma unroll
      for (int j = 0; j < 2; ++j) {
        ra[j][0] = *(const float4*)(gAf[j] + k0 + 32);
        ra[j][1] = *(const float4*)(gAf[j] + k0 + 36);
      }
    }
    bfv8 a[4], b[4];
#pragma unroll
    for (int m = 0; m < 4; ++m)
      a[m] = *(const bfv8*)&As[(wm + m * 16 + fr) * 32 + sw];
#pragma unroll
    for (int n = 0; n < 4; ++n)
      b[n] = *(const bfv8*)&Bs[(wn + n * 16 + fr) * 32 + sw];
#pragma unroll
    for (int m = 0; m < 4; ++m)
#pragma unroll
      for (int n = 0; n < 4; ++n)
        acc[m][n] = __builtin_amdgcn_mfma_f32_16x16x32_bf16(a[m], b[n], acc[m][n], 0, 0, 0);
    __syncthreads();
  }

  const int row0 = (lane >> 4) * 4;
  const int col = lane & 15;
#pragma unroll
  for (int m = 0; m < 4; ++m) {
#pragma unroll
    for (int n = 0; n < 4; ++n) {
      int cn = bn + wn + n * 16 + col;
      float bv = bias[cn];
#pragma unroll
      for (int j = 0; j < 4; ++j) {
        int mg = bm + wm + m * 16 + row0 + j;
        if (mg < M)
          C[(size_t)mg * 256 + cn] = f2b(acc[m][n][j] + bv);
      }
    }
  }
}

// ---------------------------------------------------------------------------
// MFMA GEMM, m97-style gload_lds staging, BM templated (128 or 64), BN=128.
// AMODE 0: plain rows. 2: m=b*1800+lq -> token map row.
// OUTMODE: 0 = f32, 1 = bf16, 2 = bf16 + relu.
// ---------------------------------------------------------------------------
template<int AMODE, int OUTMODE, int BM>
__global__ __launch_bounds__(256) void gemm_mfma(
    const ushort* __restrict__ A, const ushort* __restrict__ W,
    const float* __restrict__ bias, void* __restrict__ Cv,
    int M, int N, int K) {
  constexpr int AJ = BM / 64;
  constexpr int MR = BM / 32;
  __shared__ ushort As[BM * 32];
  __shared__ ushort Bs[128 * 32];
  const int tid = threadIdx.x;
  const int bm = blockIdx.y * BM, bn = blockIdx.x * 128;
  const int wave = tid >> 6, lane = tid & 63;

  const int srow = wave * 16 + (lane >> 2);
  const ushort* gA[AJ]; ushort* lA[AJ];
  const ushort* gB[2];  ushort* lB[2];
#pragma unroll
  for (int j = 0; j < AJ; ++j) {
    int row = j * 64 + srow;
    int gch = (lane & 3) ^ (row & 3);
    int gm = bm + row; if (gm >= M) gm = M - 1;
    int asrc;
    if (AMODE == 0) {
      asrc = gm;
    } else {
      int b = gm / LQ_, lq = gm - b * LQ_;
      int qq = lq / NK_, kk = lq - qq * NK_;
      asrc = qq * (BS_ * NK_) + b * NK_ + kk;
    }
    gA[j] = A + (size_t)asrc * K + gch * 8;
    lA[j] = As + (j * 4 + wave) * 512;
  }
#pragma unroll
  for (int j = 0; j < 2; ++j) {
    int row = j * 64 + srow;
    int gch = (lane & 3) ^ (row & 3);
    gB[j] = W + (size_t)(bn + row) * K + gch * 8;
    lB[j] = Bs + (j * 4 + wave) * 512;
  }

  const int wm = (wave >> 1) * (BM / 2), wn = (wave & 1) * 64;
  const int fr = lane & 15, fk = lane >> 4;
  const int sw = (fk ^ (fr & 3)) << 3;

  f32x4 acc[MR][4] = {};
  for (int k0 = 0; k0 < K; k0 += 32) {
#pragma unroll
    for (int j = 0; j < AJ; ++j) gload16(gA[j] + k0, lA[j]);
#pragma unroll
    for (int j = 0; j < 2; ++j) gload16(gB[j] + k0, lB[j]);
    __syncthreads();
    bfv8 a[MR], b[4];
#pragma unroll
    for (int m = 0; m < MR; ++m)
      a[m] = *(const bfv8*)&As[(wm + m * 16 + fr) * 32 + sw];
#pragma unroll
    for (int n = 0; n < 4; ++n)
      b[n] = *(const bfv8*)&Bs[(wn + n * 16 + fr) * 32 + sw];
#pragma unroll
    for (int m = 0; m < MR; ++m)
#pragma unroll
      for (int n = 0; n < 4; ++n)
        acc[m][n] = __builtin_amdgcn_mfma_f32_16x16x32_bf16(a[m], b[n], acc[m][n], 0, 0, 0);
    __syncthreads();
  }

  const int row0 = (lane >> 4) * 4;
  const int col = lane & 15;
#pragma unroll
  for (int m = 0; m < MR; ++m) {
#pragma unroll
    for (int n = 0; n < 4; ++n) {
      int cn = bn + wn + n * 16 + col;
      float bv = bias[cn];
#pragma unroll
      for (int j = 0; j < 4; ++j) {
        int mg = bm + wm + m * 16 + row0 + j;
        if (mg < M) {
          float o = acc[m][n][j] + bv;
          if (OUTMODE == 2) o = fmaxf(o, 0.f);
          if (OUTMODE == 0) ((float*)Cv)[(size_t)mg * N + cn] = o;
          else ((ushort*)Cv)[(size_t)mg * N + cn] = f2b(o);
        }
      }
    }
  }
}

// ---------------------------------------------------------------------------
// Fused GEMM (N=256) + residual + LayerNorm epilogue (BM=32, bf16 residual).
// LNMODE: 0 = bf16 out + POS, 1 = bf16 out, 2 = f32 out.
// ---------------------------------------------------------------------------
template<int LNMODE>
__global__ __launch_bounds__(256) void gemm_ln(
    const ushort* __restrict__ A, const ushort* __restrict__ W,
    const float* __restrict__ bias, const ushort* __restrict__ Xb,
    const float* __restrict__ POS, const float* __restrict__ G,
    const float* __restrict__ Bb, void* __restrict__ Out, int K) {
  __shared__ float Ep[32][264];              // 33.8 KB; staging aliased below
  ushort* As = (ushort*)&Ep[0][0];           // 32x32  = 2 KB
  ushort* Bs = As + 32 * 32;                 // 256x32 = 16 KB

  const int tid = threadIdx.x;
  const int wave = tid >> 6, lane = tid & 63;
  const int bm = blockIdx.x * 32;

  const int arow = wave * 8 + (lane >> 2);
  const int agch = (lane & 3) ^ (arow & 3);
  const ushort* gA = A + (size_t)(bm + arow) * K + agch * 8;
  ushort* lA = As + wave * 256;
  const int srow = wave * 16 + (lane >> 2);
  const ushort* gB[4]; ushort* lB[4];
#pragma unroll
  for (int j = 0; j < 4; ++j) {
    int row = j * 64 + srow;
    int gch = (lane & 3) ^ (row & 3);
    gB[j] = W + (size_t)row * K + gch * 8;
    lB[j] = Bs + (j * 4 + wave) * 512;
  }

  const int wn = wave * 64;
  const int fr = lane & 15, fk = lane >> 4;
  const int sw = (fk ^ (fr & 3)) << 3;

  f32x4 acc[2][4] = {};
  for (int k0 = 0; k0 < K; k0 += 32) {
    if (lane < 32) gload16(gA + k0, lA);
#pragma unroll
    for (int j = 0; j < 4; ++j) gload16(gB[j] + k0, lB[j]);
    __syncthreads();
    bfv8 a[2], b[4];
#pragma unroll
    for (int m = 0; m < 2; ++m)
      a[m] = *(const bfv8*)&As[(m * 16 + fr) * 32 + sw];
#pragma unroll
    for (int n = 0; n < 4; ++n)
      b[n] = *(const bfv8*)&Bs[(wn + n * 16 + fr) * 32 + sw];
#pragma unroll
    for (int m = 0; m < 2; ++m)
#pragma unroll
      for (int n = 0; n < 4; ++n)
        acc[m][n] = __builtin_amdgcn_mfma_f32_16x16x32_bf16(a[m], b[n], acc[m][n], 0, 0, 0);
    __syncthreads();
  }

  const int row0 = (lane >> 4) * 4;
  const int col = lane & 15;
  float bv[4];
#pragma unroll
  for (int n = 0; n < 4; ++n) bv[n] = bias[wn + n * 16 + col];

  const float4 g4 = *(const float4*)(G + lane * 4);
  const float4 bb4 = *(const float4*)(Bb + lane * 4);

#pragma unroll
  for (int m = 0; m < 2; ++m)
#pragma unroll
    for (int n = 0; n < 4; ++n)
#pragma unroll
      for (int j = 0; j < 4; ++j)
        Ep[m * 16 + row0 + j][wn + n * 16 + col] = acc[m][n][j] + bv[n];
  __syncthreads();

  for (int rr = 0; rr < 8; ++rr) {
    int lrow = wave * 8 + rr;
    size_t off = (size_t)(bm + lrow) * 256 + lane * 4;
    float4 ev = *(const float4*)&Ep[lrow][lane * 4];
    ushort4 x4 = *(const ushort4*)(Xb + off);
    float4 v = make_float4(b2f(x4.x) + ev.x, b2f(x4.y) + ev.y,
                           b2f(x4.z) + ev.z, b2f(x4.w) + ev.w);
    float s = v.x + v.y + v.z + v.w;
#pragma unroll
    for (int o = 32; o; o >>= 1) s += __shfl_xor(s, o);
    float mu = s * (1.0f / 256.0f);
    float4 c = make_float4(v.x - mu, v.y - mu, v.z - mu, v.w - mu);
    float q = c.x * c.x + c.y * c.y + c.z * c.z + c.w * c.w;
#pragma unroll
    for (int o = 32; o; o >>= 1) q += __shfl_xor(q, o);
    float rs = rsqrtf(q * (1.0f / 256.0f) + 1e-5f);
    float4 o4;
    o4.x = c.x * rs * g4.x + bb4.x;
    o4.y = c.y * rs * g4.y + bb4.y;
    o4.z = c.z * rs * g4.z + bb4.z;
    o4.w = c.w * rs * g4.w + bb4.w;
    if (LNMODE == 0) {
      float4 pv = *(const float4*)(POS + off);
      o4.x += pv.x; o4.y += pv.y; o4.z += pv.z; o4.w += pv.w;
    }
    if (LNMODE == 2) {
      *(float4*)((float*)Out + off) = o4;
    } else {
      ushort4 ob;
      ob.x = f2b(o4.x); ob.y = f2b(o4.y); ob.z = f2b(o4.z); ob.w = f2b(o4.w);
      *(ushort4*)((ushort*)Out + off) = ob;
    }
  }
}

// ---------------------------------------------------------------------------
// Across-attention via MFMA (unchanged, known-good).
// ---------------------------------------------------------------------------
__global__ __launch_bounds__(256) void attn_across_mfma(
    const ushort* __restrict__ QKV, ushort* __restrict__ O) {
  __shared__ ushort Qs[112][40];
  __shared__ ushort Ks[112][40];
  __shared__ ushort Vt[32][136];
  __shared__ ushort Ps[112][136];
  const int b = blockIdx.x >> 3, h = blockIdx.x & 7;
  const int tid = threadIdx.x;

  for (int idx = tid; idx < 112 * 16; idx += 256) {
    int r = idx >> 4, du = (idx & 15) * 2;
    uint q = 0, k = 0;
    if (r < 100) {
      size_t base = ((size_t)r * 144 + b) * 768 + h * 32 + du;
      q = *(const uint*)(QKV + base);
      k = *(const uint*)(QKV + base + 256);
    }
    *(uint*)&Qs[r][du] = q;
    *(uint*)&Ks[r][du] = k;
  }
  for (int idx = tid; idx < 128 * 32; idx += 256) {
    int s = idx >> 5, d = idx & 31;
    ushort v = 0;
    if (s < 100) v = QKV[((size_t)s * 144 + b) * 768 + 512 + h * 32 + d];
    Vt[d][s] = v;
  }
  for (int idx = tid; idx < 112 * 8; idx += 256) {
    int r = idx >> 3, c = 112 + (idx & 7) * 2;
    *(uint*)&Ps[r][c] = 0;
  }
  __syncthreads();

  const int wave = tid >> 6, lane = tid & 63;
  const int fr = lane & 15, fk = lane >> 4;
  const float scale = 0.17677669529663687f;

#pragma unroll
  for (int mi = 0; mi < 2; ++mi) {
    const int mt = wave + mi * 4;
    if (mt < 7) {
      bfv8 aq = *(const bfv8*)&Qs[mt * 16 + fr][fk * 8];
      f32x4 sacc[7];
#pragma unroll
      for (int nt = 0; nt < 7; ++nt) {
        bfv8 bk = *(const bfv8*)&Ks[nt * 16 + fr][fk * 8];
        f32x4 z = {0.f, 0.f, 0.f, 0.f};
        sacc[nt] = __builtin_amdgcn_mfma_f32_16x16x32_bf16(aq, bk, z, 0, 0, 0);
      }
      const bool maskc = (lane & 15) >= 4;
#pragma unroll
      for (int j = 0; j < 4; ++j) {
        float v[7];
        float mx = -1e30f;
#pragma unroll
        for (int nt = 0; nt < 7; ++nt) {
          float s = sacc[nt][j] * scale;
          if (nt == 6 && maskc) s = -1e30f;
          v[nt] = s;
          mx = fmaxf(mx, s);
        }
        mx = fmaxf(mx, __shfl_xor(mx, 1));
        mx = fmaxf(mx, __shfl_xor(mx, 2));
        mx = fmaxf(mx, __shfl_xor(mx, 4));
        mx = fmaxf(mx, __shfl_xor(mx, 8));
        float sum = 0.f;
#pragma unroll
        for (int nt = 0; nt < 7; ++nt) {
          v[nt] = __expf(v[nt] - mx);
          sum += v[nt];
        }
        sum += __shfl_xor(sum, 1);
        sum += __shfl_xor(sum, 2);
        sum += __shfl_xor(sum, 4);
        sum += __shfl_xor(sum, 8);
        float inv = 1.f / sum;
        int row = mt * 16 + (lane >> 4) * 4 + j;
#pragma unroll
        for (int nt = 0; nt < 7; ++nt)
          Ps[row][nt * 16 + (lane & 15)] = f2b(v[nt] * inv);
      }
    }
  }
  __syncthreads();

  f32x4 oacc[2][2] = {};
#pragma unroll
  for (int mi = 0; mi < 2; ++mi) {
    const int mt = wave + mi * 4;
    if (mt < 7) {
#pragma unroll
      for (int ks = 0; ks < 4; ++ks) {
        bfv8 ap = *(const bfv8*)&Ps[mt * 16 + fr][ks * 32 + fk * 8];
#pragma unroll
        for (int n = 0; n < 2; ++n) {
          bfv8 bv = *(const bfv8*)&Vt[n * 16 + fr][ks * 32 + fk * 8];
          oacc[mi][n] = __builtin_amdgcn_mfma_f32_16x16x32_bf16(ap, bv, oacc[mi][n], 0, 0, 0);
        }
      }
#pragma unroll
      for (int n = 0; n < 2; ++n) {
#pragma unroll
        for (int j = 0; j < 4; ++j) {
          int q = mt * 16 + (lane >> 4) * 4 + j;
          if (q < 100) {
            O[((size_t)q * 144 + b) * 256 + h * 32 + n * 16 + (lane & 15)] =
                f2b(oacc[mi][n][j]);
          }
        }
      }
    }
  }
}

// ---------------------------------------------------------------------------
// Within-attention (unchanged, known-good).
// ---------------------------------------------------------------------------
__global__ __launch_bounds__(256) void attn_within(
    const ushort* __restrict__ QKV, ushort* __restrict__ O) {
  constexpr int ST = 258;
  __shared__ ushort Qs[18 * ST];
  __shared__ ushort Ks[18 * ST];
  __shared__ ushort Vs[18 * ST];
  const int bidx = blockIdx.x;
  const int qq = bidx >> 3, bb = bidx & 7;
  const int tid = threadIdx.x;
  for (int idx = tid; idx < 18 * 128; idx += 256) {
    int r = idx >> 7, j2 = (idx & 127) * 2;
    size_t base = ((size_t)qq * 144 + bb * 18 + r) * 768 + j2;
    *(uint*)&Qs[r * ST + j2] = *(const uint*)(QKV + base);
    *(uint*)&Ks[r * ST + j2] = *(const uint*)(QKV + base + 256);
    *(uint*)&Vs[r * ST + j2] = *(const uint*)(QKV + base + 512);
  }
  __syncthreads();
  const int wave = tid >> 6, lane = tid & 63;
  const int h = wave * 2 + (lane >> 5);
  const int li = lane & 31;
  const int hd = h * 32;
  const float scale = 0.17677669529663687f;
  const bool kv = li < 18;
  for (int s = 0; s < 18; ++s) {
    float sc = 0.f;
    if (kv) {
      const ushort* qrow = &Qs[s * ST + hd];
      const ushort* krow = &Ks[li * ST + hd];
#pragma unroll 8
      for (int d = 0; d < 32; ++d) sc += b2f(qrow[d]) * b2f(krow[d]);
    }
    sc = kv ? sc * scale : -1e30f;
    float mx = sc;
    mx = fmaxf(mx, __shfl_xor(mx, 16));
    mx = fmaxf(mx, __shfl_xor(mx, 8));
    mx = fmaxf(mx, __shfl_xor(mx, 4));
    mx = fmaxf(mx, __shfl_xor(mx, 2));
    mx = fmaxf(mx, __shfl_xor(mx, 1));
    float e = kv ? __expf(sc - mx) : 0.f;
    float sum = e;
    sum += __shfl_xor(sum, 16);
    sum += __shfl_xor(sum, 8);
    sum += __shfl_xor(sum, 4);
    sum += __shfl_xor(sum, 2);
    sum += __shfl_xor(sum, 1);
    float p = e / sum;
    float o = 0.f;
    const int half = lane & 32;
#pragma unroll
    for (int k = 0; k < 18; ++k) {
      float pk = __shfl(p, half + k);
      o += pk * b2f(Vs[k * ST + hd + li]);
    }
    O[((size_t)qq * 144 + bb * 18 + s) * 256 + hd + li] = f2b(o);
  }
}

// ---------------------------------------------------------------------------
// Deformable sampling, two-phase (unchanged, known-good).
// ---------------------------------------------------------------------------
__global__ __launch_bounds__(256) void deform_sample(
    const float* __restrict__ OFFAW, const ushort* __restrict__ V,
    const float* __restrict__ REF, ushort* __restrict__ OUT) {
  __shared__ uint2 sDesc[32 * 65];
  const int tid = threadIdx.x;
  const int m0 = blockIdx.x * 4;

  const int WH[4] = {100, 50, 25, 13};
  const int STl[4] = {0, 10000, 12500, 13125};

#pragma unroll
  for (int dd = 0; dd < 2; ++dd) {
    const int desc = tid + dd * 256;
    const int g = desc >> 7, rem = desc & 127;
    const int h = rem >> 4, lp = rem & 15, li = lp >> 2, p = lp & 3;
    const int m = m0 + g;
    const int b = m / LQ_, lq = m - b * LQ_;

    float awv = OFFAW[(size_t)m * 384 + 256 + h * 16 + lp];
    float mx = awv;
    mx = fmaxf(mx, __shfl_xor(mx, 8, 16));
    mx = fmaxf(mx, __shfl_xor(mx, 4, 16));
    mx = fmaxf(mx, __shfl_xor(mx, 2, 16));
    mx = fmaxf(mx, __shfl_xor(mx, 1, 16));
    float e = __expf(awv - mx);
    float sm = e;
    sm += __shfl_xor(sm, 8, 16);
    sm += __shfl_xor(sm, 4, 16);
    sm += __shfl_xor(sm, 2, 16);
    sm += __shfl_xor(sm, 1, 16);
    const float aw = e / sm;

    const float* offp = OFFAW + (size_t)m * 384 + h * 32 + li * 8 + p * 2;
    const float ox = offp[0], oy = offp[1];
    const float rx = REF[(((size_t)lq * 8 + b) * 4 + li) * 2 + 0];
    const float ry = REF[(((size_t)lq * 8 + b) * 4 + li) * 2 + 1];
    const int Wl = WH[li], st = STl[li];
    const float fW = (float)Wl;
    const float x = fmaf(rx, fW, ox) - 0.5f;
    const float y = fmaf(ry, fW, oy) - 0.5f;
    const float x0f = floorf(x), y0f = floorf(y);
    const float lx = x - x0f, ly = y - y0f;
    const int x0 = (int)x0f, y0 = (int)y0f;
    const int base = (g * 8 + h) * 65 + lp * 4;
#pragma unroll
    for (int c = 0; c < 4; ++c) {
      const int cx = c & 1, cy = c >> 1;
      const int xi = x0 + cx, yi = y0 + cy;
      const bool va = (xi >= 0) && (xi < Wl) && (yi >= 0) && (yi < Wl);
      const int xc = min(max(xi, 0), Wl - 1);
      const int yc = min(max(yi, 0), Wl - 1);
      const float wx = cx ? lx : (1.f - lx);
      const float wy = cy ? ly : (1.f - ly);
      const float wgt = va ? aw * wx * wy : 0.f;
      uint2 dv;
      dv.x = (uint)(st + yc * Wl + xc);
      dv.y = __builtin_bit_cast(uint, wgt);
      sDesc[base + c] = dv;
    }
  }
  __syncthreads();

  const int g = tid >> 6;
  const int h = (tid >> 3) & 7;
  const int d4 = (tid & 7) * 4;
  const int m = m0 + g;
  const int b = m / LQ_, lq = m - b * LQ_;
  const int qq = lq / NK_, kk = lq - qq * NK_;
  const ushort* Vg = V + ((size_t)b * LIN_) * 256 + h * 32 + d4;
  const int dbase = (g * 8 + h) * 65;
  float a0 = 0.f, a1 = 0.f, a2 = 0.f, a3 = 0.f;
#pragma unroll
  for (int lp = 0; lp < 16; ++lp) {
#pragma unroll
    for (int c = 0; c < 4; ++c) {
      const uint2 dv = sDesc[dbase + lp * 4 + c];
      const float w = __builtin_bit_cast(float, dv.y);
      const ushort4 v = *(const ushort4*)(Vg + (size_t)dv.x * 256);
      a0 = fmaf(w, b2f(v.x), a0);
      a1 = fmaf(w, b2f(v.y), a1);
      a2 = fmaf(w, b2f(v.z), a2);
      a3 = fmaf(w, b2f(v.w), a3);
    }
  }
  const size_t tok = (size_t)qq * 144 + b * 18 + kk;
  ushort4 o;
  o.x = f2b(a0); o.y = f2b(a1); o.z = f2b(a2); o.w = f2b(a3);
  *(ushort4*)(OUT + tok * 256 + h * 32 + d4) = o;
}

// ---------------------------------------------------------------------------
extern "C" void kernel_launch(void* const* d_in, const int* in_sizes, int n_in,
                              void* d_out, int out_size, void* d_ws, size_t ws_size,
                              hipStream_t stream) {
  const float* tgt  = (const float*)d_in[0];
  const float* pos  = (const float*)d_in[1];
  const float* ref  = (const float*)d_in[2];
  const float* mem  = (const float*)d_in[3];
  const float* across_in_w  = (const float*)d_in[4];
  const float* across_in_b  = (const float*)d_in[5];
  const float* across_out_w = (const float*)d_in[6];
  const float* across_out_b = (const float*)d_in[7];
  const float* within_in_w  = (const float*)d_in[8];
  const float* within_in_b  = (const float*)d_in[9];
  const float* within_out_w = (const float*)d_in[10];
  const float* within_out_b = (const float*)d_in[11];
  const float* off_w  = (const float*)d_in[12];
  const float* off_b  = (const float*)d_in[13];
  const float* aw_w   = (const float*)d_in[14];
  const float* aw_b   = (const float*)d_in[15];
  const float* val_w  = (const float*)d_in[16];
  const float* val_b  = (const float*)d_in[17];
  const float* msout_w = (const float*)d_in[18];
  const float* msout_b = (const float*)d_in[19];
  const float* lin1_w  = (const float*)d_in[20];
  const float* lin1_b  = (const float*)d_in[21];
  const float* lin2_w  = (const float*)d_in[22];
  const float* lin2_b  = (const float*)d_in[23];
  const float* lin1p_w = (const float*)d_in[24];
  const float* lin1p_b = (const float*)d_in[25];
  const float* lin2p_w = (const float*)d_in[26];
  const float* lin2p_b = (const float*)d_in[27];
  const float* across_norm_g = (const float*)d_in[28];
  const float* across_norm_b = (const float*)d_in[29];
  const float* within_norm_g = (const float*)d_in[30];
  const float* within_norm_b = (const float*)d_in[31];
  const float* norm1_g = (const float*)d_in[32];
  const float* norm1_b = (const float*)d_in[33];
  const float* norm2_g = (const float*)d_in[34];
  const float* norm2_b = (const float*)d_in[35];
  const float* norm2p_g = (const float*)d_in[36];
  const float* norm2p_b = (const float*)d_in[37];

  // ---- workspace layout (QKVb/R1 and tgtb/OFFAW share) ----
  char* w = (char*)d_ws;
  ushort* Wb    = (ushort*)w;  w += 3604480;                         // weights bf16
  ushort* QKVb  = (ushort*)w;  w += (size_t)(BS_ * LIN_) * 256 * 2;  // 54.5MB region (QKV uses 22.1MB)
  ushort* AOb   = (ushort*)w;  w += (size_t)T_ * 256 * 2;            // 7.37MB (also SMPb)
  ushort* CTb   = (ushort*)w;  w += (size_t)T_ * 256 * 2;            // 7.37MB (bf16 residual stream)
  ushort* Vb    = (ushort*)w;  w += (size_t)(BS_ * LIN_) * 256 * 2;  // 54.5MB (also Uff)
  float*  R2    = (float*)w;   w += (size_t)T_ * 384 * 4;            // 22.1MB: tgtb then OFFAW
  float*  OAB   = (float*)w;   w += 384 * 4;
  ushort* tgtb  = (ushort*)R2;
  float*  OFFAW = R2;       // written after tgtb's last use (step 5; tgtb last read in step 4)
  ushort* Uff   = Vb;
  ushort* SMPb  = AOb;

  ushort* W_across_in  = Wb + WOF0;
  ushort* W_within_in  = Wb + WOF1;
  ushort* W_across_out = Wb + WOF2;
  ushort* W_within_out = Wb + WOF3;
  ushort* W_offaw      = Wb + WOF4;   // off rows 0..255, aw rows 256..383
  ushort* W_val        = Wb + WOF6;
  ushort* W_msout      = Wb + WOF7;
  ushort* W_lin1       = Wb + WOF8;
  ushort* W_lin2       = Wb + WOF9;
  ushort* W_lin1p      = Wb + WOF10;
  ushort* W_lin2p      = Wb + WOF11;

  dim3 blk(256);
  const int MT = T_;                 // 14400
  const int MV = BS_ * LIN_;         // 106352
  const int MVt = (MV + 127) / 128;  // 831 (BM=128 vproj grid)
  const int MT64 = MT / 64;          // 225 (BM=64 GEMM grid)
  const int MT32 = MT / 32;          // 450 (gemm_ln grid)

  // 0. conversions (weights+bias fused; tgt only — mem is read directly)
  conv_weights<<<dim3((WTOT / 8 + 255) / 256), blk, 0, stream>>>(
      across_in_w, within_in_w, across_out_w, within_out_w, off_w, aw_w,
      val_w, msout_w, lin1_w, lin2_w, lin1p_w, lin2p_w, Wb, off_b, aw_b, OAB);
  conv_tgt<<<dim3(MT * 32 / 256), blk, 0, stream>>>(tgt, tgtb);
  // 1. value projection (mem f32 direct, A-pipelined) -> Vb
  gemm_vproj<<<dim3(2, MVt), blk, 0, stream>>>(
      mem, W_val, val_b, Vb, MV);
  // 2. across in-proj -> QKVb
  gemm_mfma<0, 1, 64><<<dim3(6, MT64), blk, 0, stream>>>(
      tgtb, W_across_in, across_in_b, QKVb, MT, 768, 256);
  // 3. across attention -> AOb
  attn_across_mfma<<<dim3(144 * 8), blk, 0, stream>>>(QKVb, AOb);
  // 4. across out-proj + LN(tgtb + .) + pos -> CTb (bf16)
  gemm_ln<0><<<dim3(MT32), blk, 0, stream>>>(
      AOb, W_across_out, across_out_b, tgtb, pos,
      across_norm_g, across_norm_b, CTb, 256);
  // 5. fused off+aw (token map) -> OFFAW (overwrites tgtb; tgtb dead)
  gemm_mfma<2, 0, 64><<<dim3(3, MT64), blk, 0, stream>>>(
      CTb, W_offaw, OAB, OFFAW, MT, 384, 256);
  // 6. bilinear sampling -> SMPb
  deform_sample<<<dim3(T_ / 4), blk, 0, stream>>>(OFFAW, Vb, ref, SMPb);
  // 7. msout + norm1(CTb + .) -> CTb (in-place, block-local safe)
  gemm_ln<1><<<dim3(MT32), blk, 0, stream>>>(
      SMPb, W_msout, msout_b, CTb, nullptr,
      norm1_g, norm1_b, CTb, 256);
  // 8. lin1 (+relu) -> Uff
  gemm_mfma<0, 2, 64><<<dim3(8, MT64), blk, 0, stream>>>(
      CTb, W_lin1, lin1_b, Uff, MT, 1024, 256);
  // 9. lin2 + norm2(CTb + .) + pos -> CTb
  gemm_ln<0><<<dim3(MT32), blk, 0, stream>>>(
      Uff, W_lin2, lin2_b, CTb, pos,
      norm2_g, norm2_b, CTb, 1024);
  // 10. within in-proj -> QKVb
  gemm_mfma<0, 1, 64><<<dim3(6, MT64), blk, 0, stream>>>(
      CTb, W_within_in, within_in_b, QKVb, MT, 768, 256);
  // 11. within attention -> AOb
  attn_within<<<dim3(NQ_ * BS_), blk, 0, stream>>>(QKVb, AOb);
  // 12. within out-proj + within_norm(CTb + .) -> CTb
  gemm_ln<1><<<dim3(MT32), blk, 0, stream>>>(
      AOb, W_within_out, within_out_b, CTb, nullptr,
      within_norm_g, within_norm_b, CTb, 256);
  // 13. lin1p (+relu) -> Uff
  gemm_mfma<0, 2, 64><<<dim3(8, MT64), blk, 0, stream>>>(
      CTb, W_lin1p, lin1p_b, Uff, MT, 1024, 256);
  // 14. lin2p + norm2p(CTb + .) -> d_out (f32)
  gemm_ln<2><<<dim3(MT32), blk, 0, stream>>>(
      Uff, W_lin2p, lin2p_b, CTb, nullptr,
      norm2p_g, norm2p_b, (float*)d_out, 1024);
}

// Round 24
// 370.687 us; speedup vs baseline: 1.0168x; 1.0105x over previous
//
#include <hip/hip_runtime.h>
#include <cstdint>
#include <cstddef>

constexpr int D_   = 256;
constexpr int NK_  = 18;
constexpr int NQ_  = 100;
constexpr int BS_  = 8;
constexpr int T_   = NQ_ * BS_ * NK_;   // 14400 tokens
constexpr int LIN_ = 13294;
constexpr int LQ_  = NQ_ * NK_;         // 1800

typedef __attribute__((ext_vector_type(8))) short bfv8;
typedef __attribute__((ext_vector_type(4))) float f32x4;

__device__ __forceinline__ ushort f2b(float f) {
  uint32_t u = __builtin_bit_cast(uint32_t, f);
  u += 0x7fffu + ((u >> 16) & 1u);
  return (ushort)(u >> 16);
}
__device__ __forceinline__ float b2f(ushort h) {
  uint32_t u = ((uint32_t)h) << 16;
  return __builtin_bit_cast(float, u);
}
__device__ __forceinline__ uint pk2(float lo, float hi) {
  return (uint)f2b(lo) | ((uint)f2b(hi) << 16);
}
// async global -> LDS, 16B per lane; lds base must be wave-uniform.
__device__ __forceinline__ void gload16(const ushort* g, ushort* l) {
  __builtin_amdgcn_global_load_lds(
      (const __attribute__((address_space(1))) void*)g,
      (__attribute__((address_space(3))) void*)l, 16, 0, 0);
}

// ---------------------------------------------------------------------------
// Weight conversion arena offsets (off_w + aw_w adjacent -> fused N=384).
// ---------------------------------------------------------------------------
constexpr int WOF0  = 0;        // across_in_w 196608
constexpr int WOF1  = 196608;   // within_in_w 196608
constexpr int WOF2  = 393216;   // across_out_w 65536
constexpr int WOF3  = 458752;   // within_out_w 65536
constexpr int WOF4  = 524288;   // off_w 65536
constexpr int WOF5  = 589824;   // aw_w 32768
constexpr int WOF6  = 622592;   // val_w 65536
constexpr int WOF7  = 688128;   // msout_w 65536
constexpr int WOF8  = 753664;   // lin1_w 262144
constexpr int WOF9  = 1015808;  // lin2_w 262144
constexpr int WOF10 = 1277952;  // lin1p_w 262144
constexpr int WOF11 = 1540096;  // lin2p_w 262144
constexpr int WTOT  = 1802240;

// Weights f32->bf16; block 0 additionally packs the fused off/aw bias.
__global__ __launch_bounds__(256) void conv_weights(
    const float* __restrict__ w0, const float* __restrict__ w1,
    const float* __restrict__ w2, const float* __restrict__ w3,
    const float* __restrict__ w4, const float* __restrict__ w5,
    const float* __restrict__ w6, const float* __restrict__ w7,
    const float* __restrict__ w8, const float* __restrict__ w9,
    const float* __restrict__ w10, const float* __restrict__ w11,
    ushort* __restrict__ out,
    const float* __restrict__ off_b, const float* __restrict__ aw_b,
    float* __restrict__ oab) {
  if (blockIdx.x == 0) {
    int t = threadIdx.x;
    oab[t] = (t < 256) ? off_b[t] : aw_b[t - 256];
    oab[t + 128] = (t + 128 < 256) ? off_b[t + 128] : aw_b[t - 128];
  }
  int i8 = (blockIdx.x * 256 + threadIdx.x) * 8;
  if (i8 >= WTOT) return;
  const float* src; int off;
  if      (i8 < WOF1)  { src = w0;  off = WOF0; }
  else if (i8 < WOF2)  { src = w1;  off = WOF1; }
  else if (i8 < WOF3)  { src = w2;  off = WOF2; }
  else if (i8 < WOF4)  { src = w3;  off = WOF3; }
  else if (i8 < WOF5)  { src = w4;  off = WOF4; }
  else if (i8 < WOF6)  { src = w5;  off = WOF5; }
  else if (i8 < WOF7)  { src = w6;  off = WOF6; }
  else if (i8 < WOF8)  { src = w7;  off = WOF7; }
  else if (i8 < WOF9)  { src = w8;  off = WOF8; }
  else if (i8 < WOF10) { src = w9;  off = WOF9; }
  else if (i8 < WOF11) { src = w10; off = WOF10; }
  else                 { src = w11; off = WOF11; }
  const float4 v0 = *(const float4*)(src + (i8 - off));
  const float4 v1 = *(const float4*)(src + (i8 - off) + 4);
  uint4 o;
  o.x = pk2(v0.x, v0.y); o.y = pk2(v0.z, v0.w);
  o.z = pk2(v1.x, v1.y); o.w = pk2(v1.z, v1.w);
  *(uint4*)(out + i8) = o;
}

// ---------------------------------------------------------------------------
// tgt f32 -> bf16 (mem is consumed directly by gemm_vproj).
// ---------------------------------------------------------------------------
__global__ __launch_bounds__(256) void conv_tgt(
    const float* __restrict__ tgt, ushort* __restrict__ tgtb) {
  int idx = blockIdx.x * 256 + threadIdx.x;
  int r = idx >> 5, c = (idx & 31) * 8;
  if (r >= T_) return;
  const float* p = tgt + (size_t)r * 256 + c;
  float4 v0 = *(const float4*)p, v1 = *(const float4*)(p + 4);
  uint4 o;
  o.x = pk2(v0.x, v0.y); o.y = pk2(v0.z, v0.w);
  o.z = pk2(v1.x, v1.y); o.w = pk2(v1.z, v1.w);
  *(uint4*)(tgtb + (size_t)r * 256 + c) = o;
}

// ---------------------------------------------------------------------------
// Value projection, READ-CONTIGUOUS variant: block tiles over MEM-row space
// (A reads walk a sequential 128KB region per block; no 8KB-stride scatter).
// The (i,b)->b*LIN+i reorder is applied on the WRITE side instead:
// mem row r -> out row (r&7)*LIN + (r>>3).  A registers single-depth
// pipelined; B on global_load_lds; 2-barrier BM=128/BN=128 loop.
// ---------------------------------------------------------------------------
__global__ __launch_bounds__(256) void gemm_vproj(
    const float* __restrict__ Amem, const ushort* __restrict__ W,
    const float* __restrict__ bias, ushort* __restrict__ C, int M) {
  __shared__ ushort As[128 * 32];
  __shared__ ushort Bs[128 * 32];
  const int tid = threadIdx.x;
  const int bm = blockIdx.y * 128, bn = blockIdx.x * 128;
  const int wave = tid >> 6, lane = tid & 63;

  const int srow = wave * 16 + (lane >> 2);
  const float* gAf[2]; ushort* lA[2];
  const ushort* gB[2]; ushort* lB[2];
#pragma unroll
  for (int j = 0; j < 2; ++j) {
    int row = j * 64 + srow;
    int gch = (lane & 3) ^ (row & 3);
    int gm = bm + row; if (gm >= M) gm = M - 1;   // mem row (contiguous)
    gAf[j] = Amem + (size_t)gm * 256 + gch * 8;
    lA[j] = As + (j * 4 + wave) * 512 + lane * 8;  // per-lane 16B slot
    gB[j] = W + (size_t)(bn + row) * 256 + gch * 8;
    lB[j] = Bs + (j * 4 + wave) * 512;
  }

  const int wm = (wave >> 1) * 64, wn = (wave & 1) * 64;
  const int fr = lane & 15, fk = lane >> 4;
  const int sw = (fk ^ (fr & 3)) << 3;

  float4 ra[2][2];   // pipelined A registers (2 rows x 8 floats)
#pragma unroll
  for (int j = 0; j < 2; ++j) {
    ra[j][0] = *(const float4*)(gAf[j]);
    ra[j][1] = *(const float4*)(gAf[j] + 4);
  }

  f32x4 acc[4][4] = {};
  for (int k0 = 0; k0 < 256; k0 += 32) {
#pragma unroll
    for (int j = 0; j < 2; ++j) gload16(gB[j] + k0, lB[j]);
#pragma unroll
    for (int j = 0; j < 2; ++j) {
      uint4 o;
      o.x = pk2(ra[j][0].x, ra[j][0].y); o.y = pk2(ra[j][0].z, ra[j][0].w);
      o.z = pk2(ra[j][1].x, ra[j][1].y); o.w = pk2(ra[j][1].z, ra[j][1].w);
      *(uint4*)lA[j] = o;
    }
    __syncthreads();
    if (k0 + 32 < 256) {
      // issue next A loads after the vmcnt(0) drain; latency hides under MFMA
#pragma unroll
      for (int j = 0; j < 2; ++j) {
        ra[j][0] = *(const float4*)(gAf[j] + k0 + 32);
        ra[j][1] = *(const float4*)(gAf[j] + k0 + 36);
      }
    }
    bfv8 a[4], b[4];
#pragma unroll
    for (int m = 0; m < 4; ++m)
      a[m] = *(const bfv8*)&As[(wm + m * 16 + fr) * 32 + sw];
#pragma unroll
    for (int n = 0; n < 4; ++n)
      b[n] = *(const bfv8*)&Bs[(wn + n * 16 + fr) * 32 + sw];
#pragma unroll
    for (int m = 0; m < 4; ++m)
#pragma unroll
      for (int n = 0; n < 4; ++n)
        acc[m][n] = __builtin_amdgcn_mfma_f32_16x16x32_bf16(a[m], b[n], acc[m][n], 0, 0, 0);
    __syncthreads();
  }

  const int row0 = (lane >> 4) * 4;
  const int col = lane & 15;
#pragma unroll
  for (int m = 0; m < 4; ++m) {
#pragma unroll
    for (int n = 0; n < 4; ++n) {
      int cn = bn + wn + n * 16 + col;
      float bv = bias[cn];
#pragma unroll
      for (int j = 0; j < 4; ++j) {
        int mg = bm + wm + m * 16 + row0 + j;   // mem row
        if (mg < M) {
          size_t orow = (size_t)(mg & 7) * LIN_ + (mg >> 3);  // out row b*LIN+i
          C[orow * 256 + cn] = f2b(acc[m][n][j] + bv);
        }
      }
    }
  }
}

// ---------------------------------------------------------------------------
// MFMA GEMM, m97-style gload_lds staging, BM templated (128 or 64), BN=128.
// AMODE 0: plain rows. 2: m=b*1800+lq -> token map row.
// OUTMODE: 0 = f32, 1 = bf16, 2 = bf16 + relu.
// ---------------------------------------------------------------------------
template<int AMODE, int OUTMODE, int BM>
__global__ __launch_bounds__(256) void gemm_mfma(
    const ushort* __restrict__ A, const ushort* __restrict__ W,
    const float* __restrict__ bias, void* __restrict__ Cv,
    int M, int N, int K) {
  constexpr int AJ = BM / 64;
  constexpr int MR = BM / 32;
  __shared__ ushort As[BM * 32];
  __shared__ ushort Bs[128 * 32];
  const int tid = threadIdx.x;
  const int bm = blockIdx.y * BM, bn = blockIdx.x * 128;
  const int wave = tid >> 6, lane = tid & 63;

  const int srow = wave * 16 + (lane >> 2);
  const ushort* gA[AJ]; ushort* lA[AJ];
  const ushort* gB[2];  ushort* lB[2];
#pragma unroll
  for (int j = 0; j < AJ; ++j) {
    int row = j * 64 + srow;
    int gch = (lane & 3) ^ (row & 3);
    int gm = bm + row; if (gm >= M) gm = M - 1;
    int asrc;
    if (AMODE == 0) {
      asrc = gm;
    } else {
      int b = gm / LQ_, lq = gm - b * LQ_;
      int qq = lq / NK_, kk = lq - qq * NK_;
      asrc = qq * (BS_ * NK_) + b * NK_ + kk;
    }
    gA[j] = A + (size_t)asrc * K + gch * 8;
    lA[j] = As + (j * 4 + wave) * 512;
  }
#pragma unroll
  for (int j = 0; j < 2; ++j) {
    int row = j * 64 + srow;
    int gch = (lane & 3) ^ (row & 3);
    gB[j] = W + (size_t)(bn + row) * K + gch * 8;
    lB[j] = Bs + (j * 4 + wave) * 512;
  }

  const int wm = (wave >> 1) * (BM / 2), wn = (wave & 1) * 64;
  const int fr = lane & 15, fk = lane >> 4;
  const int sw = (fk ^ (fr & 3)) << 3;

  f32x4 acc[MR][4] = {};
  for (int k0 = 0; k0 < K; k0 += 32) {
#pragma unroll
    for (int j = 0; j < AJ; ++j) gload16(gA[j] + k0, lA[j]);
#pragma unroll
    for (int j = 0; j < 2; ++j) gload16(gB[j] + k0, lB[j]);
    __syncthreads();
    bfv8 a[MR], b[4];
#pragma unroll
    for (int m = 0; m < MR; ++m)
      a[m] = *(const bfv8*)&As[(wm + m * 16 + fr) * 32 + sw];
#pragma unroll
    for (int n = 0; n < 4; ++n)
      b[n] = *(const bfv8*)&Bs[(wn + n * 16 + fr) * 32 + sw];
#pragma unroll
    for (int m = 0; m < MR; ++m)
#pragma unroll
      for (int n = 0; n < 4; ++n)
        acc[m][n] = __builtin_amdgcn_mfma_f32_16x16x32_bf16(a[m], b[n], acc[m][n], 0, 0, 0);
    __syncthreads();
  }

  const int row0 = (lane >> 4) * 4;
  const int col = lane & 15;
#pragma unroll
  for (int m = 0; m < MR; ++m) {
#pragma unroll
    for (int n = 0; n < 4; ++n) {
      int cn = bn + wn + n * 16 + col;
      float bv = bias[cn];
#pragma unroll
      for (int j = 0; j < 4; ++j) {
        int mg = bm + wm + m * 16 + row0 + j;
        if (mg < M) {
          float o = acc[m][n][j] + bv;
          if (OUTMODE == 2) o = fmaxf(o, 0.f);
          if (OUTMODE == 0) ((float*)Cv)[(size_t)mg * N + cn] = o;
          else ((ushort*)Cv)[(size_t)mg * N + cn] = f2b(o);
        }
      }
    }
  }
}

// ---------------------------------------------------------------------------
// Fused GEMM (N=256) + residual + LayerNorm epilogue (BM=32, bf16 residual).
// LNMODE: 0 = bf16 out + POS, 1 = bf16 out, 2 = f32 out.
// ---------------------------------------------------------------------------
template<int LNMODE>
__global__ __launch_bounds__(256) void gemm_ln(
    const ushort* __restrict__ A, const ushort* __restrict__ W,
    const float* __restrict__ bias, const ushort* __restrict__ Xb,
    const float* __restrict__ POS, const float* __restrict__ G,
    const float* __restrict__ Bb, void* __restrict__ Out, int K) {
  __shared__ float Ep[32][264];              // 33.8 KB; staging aliased below
  ushort* As = (ushort*)&Ep[0][0];           // 32x32  = 2 KB
  ushort* Bs = As + 32 * 32;                 // 256x32 = 16 KB

  const int tid = threadIdx.x;
  const int wave = tid >> 6, lane = tid & 63;
  const int bm = blockIdx.x * 32;

  const int arow = wave * 8 + (lane >> 2);
  const int agch = (lane & 3) ^ (arow & 3);
  const ushort* gA = A + (size_t)(bm + arow) * K + agch * 8;
  ushort* lA = As + wave * 256;
  const int srow = wave * 16 + (lane >> 2);
  const ushort* gB[4]; ushort* lB[4];
#pragma unroll
  for (int j = 0; j < 4; ++j) {
    int row = j * 64 + srow;
    int gch = (lane & 3) ^ (row & 3);
    gB[j] = W + (size_t)row * K + gch * 8;
    lB[j] = Bs + (j * 4 + wave) * 512;
  }

  const int wn = wave * 64;
  const int fr = lane & 15, fk = lane >> 4;
  const int sw = (fk ^ (fr & 3)) << 3;

  f32x4 acc[2][4] = {};
  for (int k0 = 0; k0 < K; k0 += 32) {
    if (lane < 32) gload16(gA + k0, lA);
#pragma unroll
    for (int j = 0; j < 4; ++j) gload16(gB[j] + k0, lB[j]);
    __syncthreads();
    bfv8 a[2], b[4];
#pragma unroll
    for (int m = 0; m < 2; ++m)
      a[m] = *(const bfv8*)&As[(m * 16 + fr) * 32 + sw];
#pragma unroll
    for (int n = 0; n < 4; ++n)
      b[n] = *(const bfv8*)&Bs[(wn + n * 16 + fr) * 32 + sw];
#pragma unroll
    for (int m = 0; m < 2; ++m)
#pragma unroll
      for (int n = 0; n < 4; ++n)
        acc[m][n] = __builtin_amdgcn_mfma_f32_16x16x32_bf16(a[m], b[n], acc[m][n], 0, 0, 0);
    __syncthreads();
  }

  const int row0 = (lane >> 4) * 4;
  const int col = lane & 15;
  float bv[4];
#pragma unroll
  for (int n = 0; n < 4; ++n) bv[n] = bias[wn + n * 16 + col];

  const float4 g4 = *(const float4*)(G + lane * 4);
  const float4 bb4 = *(const float4*)(Bb + lane * 4);

#pragma unroll
  for (int m = 0; m < 2; ++m)
#pragma unroll
    for (int n = 0; n < 4; ++n)
#pragma unroll
      for (int j = 0; j < 4; ++j)
        Ep[m * 16 + row0 + j][wn + n * 16 + col] = acc[m][n][j] + bv[n];
  __syncthreads();

  for (int rr = 0; rr < 8; ++rr) {
    int lrow = wave * 8 + rr;
    size_t off = (size_t)(bm + lrow) * 256 + lane * 4;
    float4 ev = *(const float4*)&Ep[lrow][lane * 4];
    ushort4 x4 = *(const ushort4*)(Xb + off);
    float4 v = make_float4(b2f(x4.x) + ev.x, b2f(x4.y) + ev.y,
                           b2f(x4.z) + ev.z, b2f(x4.w) + ev.w);
    float s = v.x + v.y + v.z + v.w;
#pragma unroll
    for (int o = 32; o; o >>= 1) s += __shfl_xor(s, o);
    float mu = s * (1.0f / 256.0f);
    float4 c = make_float4(v.x - mu, v.y - mu, v.z - mu, v.w - mu);
    float q = c.x * c.x + c.y * c.y + c.z * c.z + c.w * c.w;
#pragma unroll
    for (int o = 32; o; o >>= 1) q += __shfl_xor(q, o);
    float rs = rsqrtf(q * (1.0f / 256.0f) + 1e-5f);
    float4 o4;
    o4.x = c.x * rs * g4.x + bb4.x;
    o4.y = c.y * rs * g4.y + bb4.y;
    o4.z = c.z * rs * g4.z + bb4.z;
    o4.w = c.w * rs * g4.w + bb4.w;
    if (LNMODE == 0) {
      float4 pv = *(const float4*)(POS + off);
      o4.x += pv.x; o4.y += pv.y; o4.z += pv.z; o4.w += pv.w;
    }
    if (LNMODE == 2) {
      *(float4*)((float*)Out + off) = o4;
    } else {
      ushort4 ob;
      ob.x = f2b(o4.x); ob.y = f2b(o4.y); ob.z = f2b(o4.z); ob.w = f2b(o4.w);
      *(ushort4*)((ushort*)Out + off) = ob;
    }
  }
}

// ---------------------------------------------------------------------------
// Across-attention via MFMA (unchanged, known-good).
// ---------------------------------------------------------------------------
__global__ __launch_bounds__(256) void attn_across_mfma(
    const ushort* __restrict__ QKV, ushort* __restrict__ O) {
  __shared__ ushort Qs[112][40];
  __shared__ ushort Ks[112][40];
  __shared__ ushort Vt[32][136];
  __shared__ ushort Ps[112][136];
  const int b = blockIdx.x >> 3, h = blockIdx.x & 7;
  const int tid = threadIdx.x;

  for (int idx = tid; idx < 112 * 16; idx += 256) {
    int r = idx >> 4, du = (idx & 15) * 2;
    uint q = 0, k = 0;
    if (r < 100) {
      size_t base = ((size_t)r * 144 + b) * 768 + h * 32 + du;
      q = *(const uint*)(QKV + base);
      k = *(const uint*)(QKV + base + 256);
    }
    *(uint*)&Qs[r][du] = q;
    *(uint*)&Ks[r][du] = k;
  }
  for (int idx = tid; idx < 128 * 32; idx += 256) {
    int s = idx >> 5, d = idx & 31;
    ushort v = 0;
    if (s < 100) v = QKV[((size_t)s * 144 + b) * 768 + 512 + h * 32 + d];
    Vt[d][s] = v;
  }
  for (int idx = tid; idx < 112 * 8; idx += 256) {
    int r = idx >> 3, c = 112 + (idx & 7) * 2;
    *(uint*)&Ps[r][c] = 0;
  }
  __syncthreads();

  const int wave = tid >> 6, lane = tid & 63;
  const int fr = lane & 15, fk = lane >> 4;
  const float scale = 0.17677669529663687f;

#pragma unroll
  for (int mi = 0; mi < 2; ++mi) {
    const int mt = wave + mi * 4;
    if (mt < 7) {
      bfv8 aq = *(const bfv8*)&Qs[mt * 16 + fr][fk * 8];
      f32x4 sacc[7];
#pragma unroll
      for (int nt = 0; nt < 7; ++nt) {
        bfv8 bk = *(const bfv8*)&Ks[nt * 16 + fr][fk * 8];
        f32x4 z = {0.f, 0.f, 0.f, 0.f};
        sacc[nt] = __builtin_amdgcn_mfma_f32_16x16x32_bf16(aq, bk, z, 0, 0, 0);
      }
      const bool maskc = (lane & 15) >= 4;
#pragma unroll
      for (int j = 0; j < 4; ++j) {
        float v[7];
        float mx = -1e30f;
#pragma unroll
        for (int nt = 0; nt < 7; ++nt) {
          float s = sacc[nt][j] * scale;
          if (nt == 6 && maskc) s = -1e30f;
          v[nt] = s;
          mx = fmaxf(mx, s);
        }
        mx = fmaxf(mx, __shfl_xor(mx, 1));
        mx = fmaxf(mx, __shfl_xor(mx, 2));
        mx = fmaxf(mx, __shfl_xor(mx, 4));
        mx = fmaxf(mx, __shfl_xor(mx, 8));
        float sum = 0.f;
#pragma unroll
        for (int nt = 0; nt < 7; ++nt) {
          v[nt] = __expf(v[nt] - mx);
          sum += v[nt];
        }
        sum += __shfl_xor(sum, 1);
        sum += __shfl_xor(sum, 2);
        sum += __shfl_xor(sum, 4);
        sum += __shfl_xor(sum, 8);
        float inv = 1.f / sum;
        int row = mt * 16 + (lane >> 4) * 4 + j;
#pragma unroll
        for (int nt = 0; nt < 7; ++nt)
          Ps[row][nt * 16 + (lane & 15)] = f2b(v[nt] * inv);
      }
    }
  }
  __syncthreads();

  f32x4 oacc[2][2] = {};
#pragma unroll
  for (int mi = 0; mi < 2; ++mi) {
    const int mt = wave + mi * 4;
    if (mt < 7) {
#pragma unroll
      for (int ks = 0; ks < 4; ++ks) {
        bfv8 ap = *(const bfv8*)&Ps[mt * 16 + fr][ks * 32 + fk * 8];
#pragma unroll
        for (int n = 0; n < 2; ++n) {
          bfv8 bv = *(const bfv8*)&Vt[n * 16 + fr][ks * 32 + fk * 8];
          oacc[mi][n] = __builtin_amdgcn_mfma_f32_16x16x32_bf16(ap, bv, oacc[mi][n], 0, 0, 0);
        }
      }
#pragma unroll
      for (int n = 0; n < 2; ++n) {
#pragma unroll
        for (int j = 0; j < 4; ++j) {
          int q = mt * 16 + (lane >> 4) * 4 + j;
          if (q < 100) {
            O[((size_t)q * 144 + b) * 256 + h * 32 + n * 16 + (lane & 15)] =
                f2b(oacc[mi][n][j]);
          }
        }
      }
    }
  }
}

// ---------------------------------------------------------------------------
// Within-attention (unchanged, known-good).
// ---------------------------------------------------------------------------
__global__ __launch_bounds__(256) void attn_within(
    const ushort* __restrict__ QKV, ushort* __restrict__ O) {
  constexpr int ST = 258;
  __shared__ ushort Qs[18 * ST];
  __shared__ ushort Ks[18 * ST];
  __shared__ ushort Vs[18 * ST];
  const int bidx = blockIdx.x;
  const int qq = bidx >> 3, bb = bidx & 7;
  const int tid = threadIdx.x;
  for (int idx = tid; idx < 18 * 128; idx += 256) {
    int r = idx >> 7, j2 = (idx & 127) * 2;
    size_t base = ((size_t)qq * 144 + bb * 18 + r) * 768 + j2;
    *(uint*)&Qs[r * ST + j2] = *(const uint*)(QKV + base);
    *(uint*)&Ks[r * ST + j2] = *(const uint*)(QKV + base + 256);
    *(uint*)&Vs[r * ST + j2] = *(const uint*)(QKV + base + 512);
  }
  __syncthreads();
  const int wave = tid >> 6, lane = tid & 63;
  const int h = wave * 2 + (lane >> 5);
  const int li = lane & 31;
  const int hd = h * 32;
  const float scale = 0.17677669529663687f;
  const bool kv = li < 18;
  for (int s = 0; s < 18; ++s) {
    float sc = 0.f;
    if (kv) {
      const ushort* qrow = &Qs[s * ST + hd];
      const ushort* krow = &Ks[li * ST + hd];
#pragma unroll 8
      for (int d = 0; d < 32; ++d) sc += b2f(qrow[d]) * b2f(krow[d]);
    }
    sc = kv ? sc * scale : -1e30f;
    float mx = sc;
    mx = fmaxf(mx, __shfl_xor(mx, 16));
    mx = fmaxf(mx, __shfl_xor(mx, 8));
    mx = fmaxf(mx, __shfl_xor(mx, 4));
    mx = fmaxf(mx, __shfl_xor(mx, 2));
    mx = fmaxf(mx, __shfl_xor(mx, 1));
    float e = kv ? __expf(sc - mx) : 0.f;
    float sum = e;
    sum += __shfl_xor(sum, 16);
    sum += __shfl_xor(sum, 8);
    sum += __shfl_xor(sum, 4);
    sum += __shfl_xor(sum, 2);
    sum += __shfl_xor(sum, 1);
    float p = e / sum;
    float o = 0.f;
    const int half = lane & 32;
#pragma unroll
    for (int k = 0; k < 18; ++k) {
      float pk = __shfl(p, half + k);
      o += pk * b2f(Vs[k * ST + hd + li]);
    }
    O[((size_t)qq * 144 + bb * 18 + s) * 256 + hd + li] = f2b(o);
  }
}

// ---------------------------------------------------------------------------
// Deformable sampling, two-phase (unchanged, known-good).
// ---------------------------------------------------------------------------
__global__ __launch_bounds__(256) void deform_sample(
    const float* __restrict__ OFFAW, const ushort* __restrict__ V,
    const float* __restrict__ REF, ushort* __restrict__ OUT) {
  __shared__ uint2 sDesc[32 * 65];
  const int tid = threadIdx.x;
  const int m0 = blockIdx.x * 4;

  const int WH[4] = {100, 50, 25, 13};
  const int STl[4] = {0, 10000, 12500, 13125};

#pragma unroll
  for (int dd = 0; dd < 2; ++dd) {
    const int desc = tid + dd * 256;
    const int g = desc >> 7, rem = desc & 127;
    const int h = rem >> 4, lp = rem & 15, li = lp >> 2, p = lp & 3;
    const int m = m0 + g;
    const int b = m / LQ_, lq = m - b * LQ_;

    float awv = OFFAW[(size_t)m * 384 + 256 + h * 16 + lp];
    float mx = awv;
    mx = fmaxf(mx, __shfl_xor(mx, 8, 16));
    mx = fmaxf(mx, __shfl_xor(mx, 4, 16));
    mx = fmaxf(mx, __shfl_xor(mx, 2, 16));
    mx = fmaxf(mx, __shfl_xor(mx, 1, 16));
    float e = __expf(awv - mx);
    float sm = e;
    sm += __shfl_xor(sm, 8, 16);
    sm += __shfl_xor(sm, 4, 16);
    sm += __shfl_xor(sm, 2, 16);
    sm += __shfl_xor(sm, 1, 16);
    const float aw = e / sm;

    const float* offp = OFFAW + (size_t)m * 384 + h * 32 + li * 8 + p * 2;
    const float ox = offp[0], oy = offp[1];
    const float rx = REF[(((size_t)lq * 8 + b) * 4 + li) * 2 + 0];
    const float ry = REF[(((size_t)lq * 8 + b) * 4 + li) * 2 + 1];
    const int Wl = WH[li], st = STl[li];
    const float fW = (float)Wl;
    const float x = fmaf(rx, fW, ox) - 0.5f;
    const float y = fmaf(ry, fW, oy) - 0.5f;
    const float x0f = floorf(x), y0f = floorf(y);
    const float lx = x - x0f, ly = y - y0f;
    const int x0 = (int)x0f, y0 = (int)y0f;
    const int base = (g * 8 + h) * 65 + lp * 4;
#pragma unroll
    for (int c = 0; c < 4; ++c) {
      const int cx = c & 1, cy = c >> 1;
      const int xi = x0 + cx, yi = y0 + cy;
      const bool va = (xi >= 0) && (xi < Wl) && (yi >= 0) && (yi < Wl);
      const int xc = min(max(xi, 0), Wl - 1);
      const int yc = min(max(yi, 0), Wl - 1);
      const float wx = cx ? lx : (1.f - lx);
      const float wy = cy ? ly : (1.f - ly);
      const float wgt = va ? aw * wx * wy : 0.f;
      uint2 dv;
      dv.x = (uint)(st + yc * Wl + xc);
      dv.y = __builtin_bit_cast(uint, wgt);
      sDesc[base + c] = dv;
    }
  }
  __syncthreads();

  const int g = tid >> 6;
  const int h = (tid >> 3) & 7;
  const int d4 = (tid & 7) * 4;
  const int m = m0 + g;
  const int b = m / LQ_, lq = m - b * LQ_;
  const int qq = lq / NK_, kk = lq - qq * NK_;
  const ushort* Vg = V + ((size_t)b * LIN_) * 256 + h * 32 + d4;
  const int dbase = (g * 8 + h) * 65;
  float a0 = 0.f, a1 = 0.f, a2 = 0.f, a3 = 0.f;
#pragma unroll
  for (int lp = 0; lp < 16; ++lp) {
#pragma unroll
    for (int c = 0; c < 4; ++c) {
      const uint2 dv = sDesc[dbase + lp * 4 + c];
      const float w = __builtin_bit_cast(float, dv.y);
      const ushort4 v = *(const ushort4*)(Vg + (size_t)dv.x * 256);
      a0 = fmaf(w, b2f(v.x), a0);
      a1 = fmaf(w, b2f(v.y), a1);
      a2 = fmaf(w, b2f(v.z), a2);
      a3 = fmaf(w, b2f(v.w), a3);
    }
  }
  const size_t tok = (size_t)qq * 144 + b * 18 + kk;
  ushort4 o;
  o.x = f2b(a0); o.y = f2b(a1); o.z = f2b(a2); o.w = f2b(a3);
  *(ushort4*)(OUT + tok * 256 + h * 32 + d4) = o;
}

// ---------------------------------------------------------------------------
extern "C" void kernel_launch(void* const* d_in, const int* in_sizes, int n_in,
                              void* d_out, int out_size, void* d_ws, size_t ws_size,
                              hipStream_t stream) {
  const float* tgt  = (const float*)d_in[0];
  const float* pos  = (const float*)d_in[1];
  const float* ref  = (const float*)d_in[2];
  const float* mem  = (const float*)d_in[3];
  const float* across_in_w  = (const float*)d_in[4];
  const float* across_in_b  = (const float*)d_in[5];
  const float* across_out_w = (const float*)d_in[6];
  const float* across_out_b = (const float*)d_in[7];
  const float* within_in_w  = (const float*)d_in[8];
  const float* within_in_b  = (const float*)d_in[9];
  const float* within_out_w = (const float*)d_in[10];
  const float* within_out_b = (const float*)d_in[11];
  const float* off_w  = (const float*)d_in[12];
  const float* off_b  = (const float*)d_in[13];
  const float* aw_w   = (const float*)d_in[14];
  const float* aw_b   = (const float*)d_in[15];
  const float* val_w  = (const float*)d_in[16];
  const float* val_b  = (const float*)d_in[17];
  const float* msout_w = (const float*)d_in[18];
  const float* msout_b = (const float*)d_in[19];
  const float* lin1_w  = (const float*)d_in[20];
  const float* lin1_b  = (const float*)d_in[21];
  const float* lin2_w  = (const float*)d_in[22];
  const float* lin2_b  = (const float*)d_in[23];
  const float* lin1p_w = (const float*)d_in[24];
  const float* lin1p_b = (const float*)d_in[25];
  const float* lin2p_w = (const float*)d_in[26];
  const float* lin2p_b = (const float*)d_in[27];
  const float* across_norm_g = (const float*)d_in[28];
  const float* across_norm_b = (const float*)d_in[29];
  const float* within_norm_g = (const float*)d_in[30];
  const float* within_norm_b = (const float*)d_in[31];
  const float* norm1_g = (const float*)d_in[32];
  const float* norm1_b = (const float*)d_in[33];
  const float* norm2_g = (const float*)d_in[34];
  const float* norm2_b = (const float*)d_in[35];
  const float* norm2p_g = (const float*)d_in[36];
  const float* norm2p_b = (const float*)d_in[37];

  // ---- workspace layout (QKVb/R1 and tgtb/OFFAW share) ----
  char* w = (char*)d_ws;
  ushort* Wb    = (ushort*)w;  w += 3604480;                         // weights bf16
  ushort* QKVb  = (ushort*)w;  w += (size_t)(BS_ * LIN_) * 256 * 2;  // 54.5MB region (QKV uses 22.1MB)
  ushort* AOb   = (ushort*)w;  w += (size_t)T_ * 256 * 2;            // 7.37MB (also SMPb)
  ushort* CTb   = (ushort*)w;  w += (size_t)T_ * 256 * 2;            // 7.37MB (bf16 residual stream)
  ushort* Vb    = (ushort*)w;  w += (size_t)(BS_ * LIN_) * 256 * 2;  // 54.5MB (also Uff)
  float*  R2    = (float*)w;   w += (size_t)T_ * 384 * 4;            // 22.1MB: tgtb then OFFAW
  float*  OAB   = (float*)w;   w += 384 * 4;
  ushort* tgtb  = (ushort*)R2;
  float*  OFFAW = R2;       // written after tgtb's last use (step 5; tgtb last read in step 4)
  ushort* Uff   = Vb;
  ushort* SMPb  = AOb;

  ushort* W_across_in  = Wb + WOF0;
  ushort* W_within_in  = Wb + WOF1;
  ushort* W_across_out = Wb + WOF2;
  ushort* W_within_out = Wb + WOF3;
  ushort* W_offaw      = Wb + WOF4;   // off rows 0..255, aw rows 256..383
  ushort* W_val        = Wb + WOF6;
  ushort* W_msout      = Wb + WOF7;
  ushort* W_lin1       = Wb + WOF8;
  ushort* W_lin2       = Wb + WOF9;
  ushort* W_lin1p      = Wb + WOF10;
  ushort* W_lin2p      = Wb + WOF11;

  dim3 blk(256);
  const int MT = T_;                 // 14400
  const int MV = BS_ * LIN_;         // 106352
  const int MVt = (MV + 127) / 128;  // 831 (BM=128 vproj grid)
  const int MT64 = MT / 64;          // 225 (BM=64 GEMM grid)
  const int MT32 = MT / 32;          // 450 (gemm_ln grid)

  // 0. conversions (weights+bias fused; tgt only — mem is read directly)
  conv_weights<<<dim3((WTOT / 8 + 255) / 256), blk, 0, stream>>>(
      across_in_w, within_in_w, across_out_w, within_out_w, off_w, aw_w,
      val_w, msout_w, lin1_w, lin2_w, lin1p_w, lin2p_w, Wb, off_b, aw_b, OAB);
  conv_tgt<<<dim3(MT * 32 / 256), blk, 0, stream>>>(tgt, tgtb);
  // 1. value projection (mem-row tiled, contiguous reads, scattered writes)
  gemm_vproj<<<dim3(2, MVt), blk, 0, stream>>>(
      mem, W_val, val_b, Vb, MV);
  // 2. across in-proj -> QKVb
  gemm_mfma<0, 1, 64><<<dim3(6, MT64), blk, 0, stream>>>(
      tgtb, W_across_in, across_in_b, QKVb, MT, 768, 256);
  // 3. across attention -> AOb
  attn_across_mfma<<<dim3(144 * 8), blk, 0, stream>>>(QKVb, AOb);
  // 4. across out-proj + LN(tgtb + .) + pos -> CTb (bf16)
  gemm_ln<0><<<dim3(MT32), blk, 0, stream>>>(
      AOb, W_across_out, across_out_b, tgtb, pos,
      across_norm_g, across_norm_b, CTb, 256);
  // 5. fused off+aw (token map) -> OFFAW (overwrites tgtb; tgtb dead)
  gemm_mfma<2, 0, 64><<<dim3(3, MT64), blk, 0, stream>>>(
      CTb, W_offaw, OAB, OFFAW, MT, 384, 256);
  // 6. bilinear sampling -> SMPb
  deform_sample<<<dim3(T_ / 4), blk, 0, stream>>>(OFFAW, Vb, ref, SMPb);
  // 7. msout + norm1(CTb + .) -> CTb (in-place, block-local safe)
  gemm_ln<1><<<dim3(MT32), blk, 0, stream>>>(
      SMPb, W_msout, msout_b, CTb, nullptr,
      norm1_g, norm1_b, CTb, 256);
  // 8. lin1 (+relu) -> Uff
  gemm_mfma<0, 2, 64><<<dim3(8, MT64), blk, 0, stream>>>(
      CTb, W_lin1, lin1_b, Uff, MT, 1024, 256);
  // 9. lin2 + norm2(CTb + .) + pos -> CTb
  gemm_ln<0><<<dim3(MT32), blk, 0, stream>>>(
      Uff, W_lin2, lin2_b, CTb, pos,
      norm2_g, norm2_b, CTb, 1024);
  // 10. within in-proj -> QKVb
  gemm_mfma<0, 1, 64><<<dim3(6, MT64), blk, 0, stream>>>(
      CTb, W_within_in, within_in_b, QKVb, MT, 768, 256);
  // 11. within attention -> AOb
  attn_within<<<dim3(NQ_ * BS_), blk, 0, stream>>>(QKVb, AOb);
  // 12. within out-proj + within_norm(CTb + .) -> CTb
  gemm_ln<1><<<dim3(MT32), blk, 0, stream>>>(
      AOb, W_within_out, within_out_b, CTb, nullptr,
      within_norm_g, within_norm_b, CTb, 256);
  // 13. lin1p (+relu) -> Uff
  gemm_mfma<0, 2, 64><<<dim3(8, MT64), blk, 0, stream>>>(
      CTb, W_lin1p, lin1p_b, Uff, MT, 1024, 256);
  // 14. lin2p + norm2p(CTb + .) -> d_out (f32)
  gemm_ln<2><<<dim3(MT32), blk, 0, stream>>>(
      Uff, W_lin2p, lin2p_b, CTb, nullptr,
      norm2p_g, norm2p_b, (float*)d_out, 1024);
}